// Round 7
// baseline (413.899 us; speedup 1.0000x reference)
//
#include <hip/hip_runtime.h>
#include <math.h>

#define NN 10000
#define NE 100000
#define NBATCH 64

typedef short bf16x8 __attribute__((ext_vector_type(8)));
typedef float f32x4 __attribute__((ext_vector_type(4)));

__device__ __forceinline__ float lrelu(float v){ return v > 0.f ? v : 0.2f*v; }

// fp32 -> bf16 round-to-nearest-even
__device__ __forceinline__ unsigned short f2bf(float x){
  unsigned int u = __float_as_uint(x);
  u += 0x7fffu + ((u >> 16) & 1u);
  return (unsigned short)(u >> 16);
}
__device__ __forceinline__ float bf2f(unsigned short u){
  return __uint_as_float(((unsigned int)u) << 16);
}

// ---------------- prep: zero + c1 precompute + 4 weight transposes (fused) -------------
__global__ __launch_bounds__(256) void prep_kernel(
    const float* __restrict__ vp_w, const float* __restrict__ vp_b,
    const float* __restrict__ type_emb,
    const float* __restrict__ c1_wl, const float* __restrict__ c1_bl,
    const float* __restrict__ c1_wr, const float* __restrict__ c1_br,
    float* __restrict__ Ul, float* __restrict__ CTl,
    float* __restrict__ Ur, float* __restrict__ CTr,
    const float* __restrict__ c2_wl, const float* __restrict__ c2_wr,
    const float* __restrict__ c3_wl, const float* __restrict__ c3_wr,
    unsigned short* __restrict__ W2lT, unsigned short* __restrict__ W2rT,
    unsigned short* __restrict__ W3lT, unsigned short* __restrict__ W3rT,
    float* __restrict__ zbase, int zero_words)
{
  __shared__ float t[64][65];
  int b = blockIdx.x;
  int tid = threadIdx.x;
  if (b < 144){
    const float* in; unsigned short* out; int K, N, idx;
    if (b < 64)      { in=c2_wl; out=W2lT; K=1024; N=256; idx=b; }
    else if (b <128) { in=c2_wr; out=W2rT; K=1024; N=256; idx=b-64; }
    else if (b <136) { in=c3_wl; out=W3lT; K=256;  N=128; idx=b-128; }
    else             { in=c3_wr; out=W3rT; K=256;  N=128; idx=b-136; }
    int K64 = K >> 6;
    int kx = idx % K64, nx = idx / K64;
    int k0 = kx*64, n0 = nx*64;
    int lr = tid >> 4;
    int lc = (tid & 15) * 4;
#pragma unroll
    for (int i=0;i<4;++i){
      int r = lr + i*16;
      float4 v = *(const float4*)(in + (size_t)(k0+r)*N + n0 + lc);
      t[r][lc+0]=v.x; t[r][lc+1]=v.y; t[r][lc+2]=v.z; t[r][lc+3]=v.w;
    }
    __syncthreads();
    int sr = tid >> 3;
    int sc = (tid & 7) * 8;
#pragma unroll
    for (int i=0;i<2;++i){
      int n = sr + i*32;
      unsigned short tmp[8];
#pragma unroll
      for (int j=0;j<8;++j) tmp[j] = f2bf(t[sc+j][n]);
      unsigned short* op = out + (size_t)(n0+n)*K + k0 + sc;
      *(ushort4*)op       = make_ushort4(tmp[0],tmp[1],tmp[2],tmp[3]);
      *(ushort4*)(op + 4) = make_ushort4(tmp[4],tmp[5],tmp[6],tmp[7]);
    }
  } else if (b < 148){
    int j = (b-144)*256 + tid;
    float ul=0.f, c0l=0.f, c1l=0.f, ur=0.f, c0r=0.f, c1r=0.f;
    for (int k=0; k<128; ++k){
      float a = c1_wl[k*1024 + j], bb = c1_wr[k*1024 + j];
      float vw = vp_w[k], vb = vp_b[k], t0 = type_emb[k], t1 = type_emb[128+k];
      ul += vw*a; ur += vw*bb;
      c0l += (vb+t0)*a; c1l += (vb+t1)*a;
      c0r += (vb+t0)*bb; c1r += (vb+t1)*bb;
    }
    Ul[j]=ul; Ur[j]=ur;
    CTl[j]      = c0l + c1_bl[j];
    CTl[1024+j] = c1l + c1_bl[j];
    CTr[j]      = c0r + c1_br[j];
    CTr[1024+j] = c1r + c1_br[j];
  } else {
    for (int i = (b-148)*256 + tid; i < zero_words; i += 32*256)
      zbase[i] = 0.f;
  }
}

// ---------------- fused CSR build: count -> (last block) scan -> fill ----------------
__global__ __launch_bounds__(1024) void csr_kernel(
    const int* __restrict__ src, const int* __restrict__ dst, const float* __restrict__ ea,
    int* __restrict__ deg, float* __restrict__ loop_sum,
    int* __restrict__ rowptr, float* __restrict__ loop_attr,
    int* __restrict__ rowctr, int* __restrict__ srcs, float* __restrict__ eav,
    int* __restrict__ sync_)
{
  int tid = threadIdx.x;
  int e = blockIdx.x*1024 + tid;
  int d_ = 0; float eav_ = 0.f;
  bool active = e < NE;
  if (active){
    d_ = dst[e]; eav_ = ea[e];
    atomicAdd(&deg[d_], 1);
    atomicAdd(&loop_sum[d_], eav_);
  }
  __threadfence();
  __syncthreads();
  __shared__ int amlast;
  if (tid == 0) amlast = (atomicAdd(&sync_[0], 1) == (int)gridDim.x - 1);
  __syncthreads();
  if (amlast){
    __shared__ int wsum[16];
    __shared__ int carry_s;
    int lane = tid & 63, wid = tid >> 6;
    if (tid == 0) carry_s = 0;
    __syncthreads();
    for (int base = 0; base < NN; base += 1024){
      int i = base + tid;
      int v = 0; float ls = 0.f;
      if (i < NN){ v = atomicAdd(&deg[i], 0); ls = atomicAdd(&loop_sum[i], 0.f); }
      int incl = v;
#pragma unroll
      for (int off=1; off<64; off<<=1){
        int tt = __shfl_up(incl, off, 64);
        if (lane >= off) incl += tt;
      }
      if (lane == 63) wsum[wid] = incl;
      __syncthreads();
      int pre = carry_s;
      for (int w2=0; w2<wid; ++w2) pre += wsum[w2];
      if (i < NN){
        rowptr[i] = pre + incl - v;                          // exclusive scan
        loop_attr[i] = ls / fmaxf((float)v, 1.f);            // fill='mean'
      }
      __syncthreads();
      if (tid == 0){
        int t2 = 0;
        for (int w2=0; w2<16; ++w2) t2 += wsum[w2];
        carry_s += t2;
      }
      __syncthreads();
    }
    if (tid == 0) rowptr[NN] = carry_s;
    __threadfence();
    __syncthreads();
    if (tid == 0) atomicExch(&sync_[1], 1);
  }
  if (tid == 0){
    while (atomicAdd(&sync_[1], 0) == 0) __builtin_amdgcn_s_sleep(16);
  }
  __syncthreads();
  if (active){
    int p = atomicAdd(&rowptr[d_], 0) + atomicAdd(&rowctr[d_], 1);
    srcs[p] = src[e];
    eav[p] = eav_;
  }
}

// ---------------- conv1: fused GATv2, on-the-fly xl/xr, dual-stream softmax -----------
__global__ __launch_bounds__(256) void conv1_kernel(
    const int* __restrict__ rowptr, const int* __restrict__ srcs, const float* __restrict__ eav,
    const float* __restrict__ loop_attr, const float* __restrict__ x, const int* __restrict__ ntype,
    const float* __restrict__ Ul, const float* __restrict__ CTl,
    const float* __restrict__ Ur, const float* __restrict__ CTr,
    const float* __restrict__ we, const float* __restrict__ att, const float* __restrict__ bias,
    unsigned short* __restrict__ out)
{
  int n = blockIdx.x;
  int tid = threadIdx.x;
  int ch0 = tid * 4;
  float wev[4], atv[4], biv[4], ulv[4], c0l[4], c1l[4], xrv[4];
  {
    float urv[4], c0r[4], c1r[4];
#pragma unroll
    for (int v=0; v<4; ++v){
      int ch = ch0 + v;
      wev[v] = we[ch]; atv[v] = att[ch]; biv[v] = bias[ch];
      ulv[v] = Ul[ch]; c0l[v] = CTl[ch]; c1l[v] = CTl[1024+ch];
      urv[v] = Ur[ch]; c0r[v] = CTr[ch]; c1r[v] = CTr[1024+ch];
    }
    float xn = x[n];
    int tn = ntype[n];
#pragma unroll
    for (int v=0; v<4; ++v) xrv[v] = xn*urv[v] + (tn ? c1r[v] : c0r[v]);
  }
  float m0=-INFINITY, l0=0.f, A0[4]={0.f,0.f,0.f,0.f};
  float m1=-INFINITY, l1=0.f, A1[4]={0.f,0.f,0.f,0.f};
  int beg = rowptr[n], end = rowptr[n+1];
  for (int j = beg; j <= end; j += 2){     // index end = self-loop
    bool two = (j+1) <= end;
    int s0 = (j < end) ? srcs[j] : n;
    float e0 = (j < end) ? eav[j] : loop_attr[n];
    int s1 = n; float e1 = 0.f;
    if (two){ s1 = (j+1 < end) ? srcs[j+1] : n; e1 = (j+1 < end) ? eav[j+1] : loop_attr[n]; }
    float xs0 = x[s0]; int ts0 = ntype[s0];
    float xs1 = 0.f; int ts1 = 0;
    if (two){ xs1 = x[s1]; ts1 = ntype[s1]; }
    float xl0[4], xl1[4];
#pragma unroll
    for (int v=0; v<4; ++v){
      xl0[v] = xs0*ulv[v] + (ts0 ? c1l[v] : c0l[v]);
      xl1[v] = xs1*ulv[v] + (ts1 ? c1l[v] : c0l[v]);
    }
    float p0 = 0.f, p1 = 0.f;
#pragma unroll
    for (int v=0; v<4; ++v){
      p0 += atv[v]*lrelu(xl0[v] + xrv[v] + e0*wev[v]);
      p1 += atv[v]*lrelu(xl1[v] + xrv[v] + e1*wev[v]);
    }
#pragma unroll
    for (int mm=1; mm<32; mm<<=1){
      p0 += __shfl_xor(p0, mm, 64);
      p1 += __shfl_xor(p1, mm, 64);
    }
    {
      float mn = fmaxf(m0, p0), sc = __expf(m0-mn), pe = __expf(p0-mn);
      l0 = l0*sc + pe; m0 = mn;
#pragma unroll
      for (int v=0; v<4; ++v) A0[v] = A0[v]*sc + pe*xl0[v];
    }
    if (two){
      float mn = fmaxf(m1, p1), sc = __expf(m1-mn), pe = __expf(p1-mn);
      l1 = l1*sc + pe; m1 = mn;
#pragma unroll
      for (int v=0; v<4; ++v) A1[v] = A1[v]*sc + pe*xl1[v];
    }
  }
  float mn = fmaxf(m0, m1);
  float sc0 = __expf(m0-mn), sc1 = __expf(m1-mn);
  float inv = 1.f/(l0*sc0 + l1*sc1);
  size_t baseo = (size_t)n*1024 + ch0;
  ushort4 o;
  o.x = f2bf(lrelu((A0[0]*sc0 + A1[0]*sc1)*inv + biv[0]));
  o.y = f2bf(lrelu((A0[1]*sc0 + A1[1]*sc1)*inv + biv[1]));
  o.z = f2bf(lrelu((A0[2]*sc0 + A1[2]*sc1)*inv + biv[2]));
  o.w = f2bf(lrelu((A0[3]*sc0 + A1[3]*sc1)*inv + biv[3]));
  *(ushort4*)(out + baseo) = o;
}

// ---------------- generic fused GATv2 conv, dual-stream softmax ----------------
template<int H, int THREADS, int VPT, bool ONLY0, bool OUTBF, bool INBF>
__global__ __launch_bounds__(THREADS) void conv_kernel(
    const int* __restrict__ rowptr, const int* __restrict__ srcs, const float* __restrict__ eav,
    const float* __restrict__ loop_attr, const int* __restrict__ ntype,
    const void* __restrict__ Xv, int stride, int xr_off,
    const float* __restrict__ we, const float* __restrict__ att, const float* __restrict__ bias,
    void* __restrict__ out)
{
  const int HC = THREADS*VPT;
  const int TPH = THREADS/H;
  int n = blockIdx.x;
  if (ONLY0 && ntype[n] != 0) return;
  int tid = threadIdx.x;
  int ch0 = tid * VPT;
  const float* Xf = (const float*)Xv;
  const unsigned short* Xb = (const unsigned short*)Xv;
  float wev[VPT], atv[VPT], biv[VPT], xrv[VPT];
#pragma unroll
  for (int v=0; v<VPT; ++v){
    int ch = ch0+v;
    wev[v]=we[ch]; atv[v]=att[ch]; biv[v]=bias[ch];
  }
  if constexpr (INBF){
    ushort4 q = *(const ushort4*)(Xb + (size_t)n*stride + xr_off + ch0);
    xrv[0]=bf2f(q.x); xrv[1]=bf2f(q.y); xrv[2]=bf2f(q.z); xrv[3]=bf2f(q.w);
  } else {
#pragma unroll
    for (int v=0; v<VPT; ++v) xrv[v]=Xf[(size_t)n*stride + xr_off + ch0+v];
  }
  float m0=-INFINITY, l0=0.f, A0[VPT];
  float m1=-INFINITY, l1=0.f, A1[VPT];
#pragma unroll
  for (int v=0; v<VPT; ++v){ A0[v]=0.f; A1[v]=0.f; }
  int beg=rowptr[n], end=rowptr[n+1];
  for (int j=beg; j<=end; j+=2){
    bool two = (j+1) <= end;
    int s0 = (j < end) ? srcs[j] : n;
    float e0 = (j < end) ? eav[j] : loop_attr[n];
    int s1 = n; float e1 = 0.f;
    if (two){ s1 = (j+1 < end) ? srcs[j+1] : n; e1 = (j+1 < end) ? eav[j+1] : loop_attr[n]; }
    float x0[VPT], x1[VPT];
    if constexpr (INBF){
      ushort4 q0 = *(const ushort4*)(Xb + (size_t)s0*stride + ch0);
      x0[0]=bf2f(q0.x); x0[1]=bf2f(q0.y); x0[2]=bf2f(q0.z); x0[3]=bf2f(q0.w);
      if (two){
        ushort4 q1 = *(const ushort4*)(Xb + (size_t)s1*stride + ch0);
        x1[0]=bf2f(q1.x); x1[1]=bf2f(q1.y); x1[2]=bf2f(q1.z); x1[3]=bf2f(q1.w);
      } else { x1[0]=x1[1]=x1[2]=x1[3]=0.f; }
    } else if constexpr (VPT == 4){
      float4 q0 = *(const float4*)(Xf + (size_t)s0*stride + ch0);
      x0[0]=q0.x; x0[1]=q0.y; x0[2]=q0.z; x0[3]=q0.w;
      if (two){
        float4 q1 = *(const float4*)(Xf + (size_t)s1*stride + ch0);
        x1[0]=q1.x; x1[1]=q1.y; x1[2]=q1.z; x1[3]=q1.w;
      } else { x1[0]=x1[1]=x1[2]=x1[3]=0.f; }
    } else {
      float2 q0 = *(const float2*)(Xf + (size_t)s0*stride + ch0);
      x0[0]=q0.x; x0[1]=q0.y;
      if (two){
        float2 q1 = *(const float2*)(Xf + (size_t)s1*stride + ch0);
        x1[0]=q1.x; x1[1]=q1.y;
      } else { x1[0]=x1[1]=0.f; }
    }
    float p0=0.f, p1=0.f;
#pragma unroll
    for (int v=0; v<VPT; ++v){
      p0 += atv[v]*lrelu(x0[v]+xrv[v]+e0*wev[v]);
      p1 += atv[v]*lrelu(x1[v]+xrv[v]+e1*wev[v]);
    }
#pragma unroll
    for (int mm=1; mm<TPH; mm<<=1){
      p0 += __shfl_xor(p0, mm, 64);
      p1 += __shfl_xor(p1, mm, 64);
    }
    {
      float mn=fmaxf(m0,p0), sc=__expf(m0-mn), pe=__expf(p0-mn);
      l0=l0*sc+pe; m0=mn;
#pragma unroll
      for (int v=0; v<VPT; ++v) A0[v]=A0[v]*sc+pe*x0[v];
    }
    if (two){
      float mn=fmaxf(m1,p1), sc=__expf(m1-mn), pe=__expf(p1-mn);
      l1=l1*sc+pe; m1=mn;
#pragma unroll
      for (int v=0; v<VPT; ++v) A1[v]=A1[v]*sc+pe*x1[v];
    }
  }
  float mn = fmaxf(m0, m1);
  float sc0 = __expf(m0-mn), sc1 = __expf(m1-mn);
  float inv = 1.f/(l0*sc0 + l1*sc1);
  size_t baseo=(size_t)n*HC+ch0;
  if constexpr (OUTBF){
    unsigned short* ob = (unsigned short*)out;
    ushort4 o;
    o.x = f2bf(lrelu((A0[0]*sc0+A1[0]*sc1)*inv+biv[0]));
    o.y = f2bf(lrelu((A0[1]*sc0+A1[1]*sc1)*inv+biv[1]));
    o.z = f2bf(lrelu((A0[2]*sc0+A1[2]*sc1)*inv+biv[2]));
    o.w = f2bf(lrelu((A0[3]*sc0+A1[3]*sc1)*inv+biv[3]));
    *(ushort4*)(ob + baseo) = o;
  } else {
    float* of = (float*)out;
#pragma unroll
    for (int v=0; v<VPT; ++v) of[baseo+v]=lrelu((A0[v]*sc0+A1[v]*sc1)*inv+biv[v]);
  }
}

// ---------------- bf16 MFMA dual GEMM, 4-stage register pipeline ----------------
// Out[M, 2*NcH] = [A@Wl + bl | A@Wr + br]; A[M][K] bf16, WT[NcH][K] bf16.
// Block 256 thr = 4 waves (2x2); tile 64x64; wave tile 32x32 = 2x2 mfma_16x16x32,
// 4 loads / 4 MFMAs per k-step, prefetch depth 3 (4 buffer stages P/Q/R/S).
// XCD swizzle: all col-groups of one row-group on one XCD (A strip L2 reuse).
template<bool OUTBF>
__global__ __launch_bounds__(256) void gemm_dual_mfma(
    const short* __restrict__ Abf,
    const short* __restrict__ WlT, const short* __restrict__ WrT,
    const float* __restrict__ bl, const float* __restrict__ br,
    void* __restrict__ Out, int M, int K, int NcH, int cgrid, int rgrid)
{
  int id = blockIdx.x;
  int xcd = id & 7;
  int slot = id >> 3;
  int nb = slot % cgrid;
  int rowgroup = (slot / cgrid) * 8 + xcd;
  if (rowgroup >= rgrid) return;
  int row0 = rowgroup * 64;
  int NC2 = 2*NcH;
  int halfx = NcH >> 6;
  int isR = nb >= halfx;
  const short* WT = isR ? WrT : WlT;
  const float* bias = isR ? br : bl;
  int col0 = (nb - (isR ? halfx : 0)) * 64;
  int gcol0 = nb * 64;
  int tid = threadIdx.x;
  int lane = tid & 63, wave = tid >> 6;
  int wm = wave >> 1, wn = wave & 1;
  int quad = lane >> 4, l16 = lane & 15;

  int ar0 = row0 + wm*32 + l16;
  int ar1 = ar0 + 16;
  int car0 = ar0 < M ? ar0 : M-1;   // clamped rows never stored
  int car1 = ar1 < M ? ar1 : M-1;
  const short* ap0 = Abf + (size_t)car0*K + quad*8;
  const short* ap1 = Abf + (size_t)car1*K + quad*8;
  const short* bp0 = WT + (size_t)(col0 + wn*32 + l16)*K + quad*8;
  const short* bp1 = bp0 + (size_t)16*K;
  float bias0 = bias[col0 + wn*32 + l16];
  float bias1 = bias[col0 + wn*32 + 16 + l16];

  f32x4 acc00={0.f,0.f,0.f,0.f}, acc01={0.f,0.f,0.f,0.f};
  f32x4 acc10={0.f,0.f,0.f,0.f}, acc11={0.f,0.f,0.f,0.f};

  bf16x8 a0P,a1P,b0P,b1P, a0Q,a1Q,b0Q,b1Q, a0R,a1R,b0R,b1R, a0S,a1S,b0S,b1S;
  int nk = K >> 5, nkm1 = nk - 1;   // nk divisible by 4 (K=1024 or 256)

#define LD(St, ki) { int kk=(ki); kk = kk < nkm1 ? kk : nkm1; int ko = kk<<5; \
  a0##St = *(const bf16x8*)(ap0+ko); a1##St = *(const bf16x8*)(ap1+ko); \
  b0##St = *(const bf16x8*)(bp0+ko); b1##St = *(const bf16x8*)(bp1+ko); }
#define MF(St) { \
  acc00=__builtin_amdgcn_mfma_f32_16x16x32_bf16(a0##St,b0##St,acc00,0,0,0); \
  acc01=__builtin_amdgcn_mfma_f32_16x16x32_bf16(a0##St,b1##St,acc01,0,0,0); \
  acc10=__builtin_amdgcn_mfma_f32_16x16x32_bf16(a1##St,b0##St,acc10,0,0,0); \
  acc11=__builtin_amdgcn_mfma_f32_16x16x32_bf16(a1##St,b1##St,acc11,0,0,0); }

  LD(P,0) LD(Q,1) LD(R,2)
  for (int i=0; i<nk; i+=4){
    LD(S,i+3) MF(P)
    LD(P,i+4) MF(Q)
    LD(Q,i+5) MF(R)
    LD(R,i+6) MF(S)
  }
#undef LD
#undef MF

  int orow = row0 + wm*32 + quad*4;
  int oc0 = gcol0 + wn*32 + l16;
#pragma unroll
  for (int r = 0; r < 4; ++r){
    int rr = orow + r;
    int rr2 = rr + 16;
    if constexpr (OUTBF){
      unsigned short* ob = (unsigned short*)Out;
      if (rr < M){
        ob[(size_t)rr*NC2 + oc0]      = f2bf(acc00[r] + bias0);
        ob[(size_t)rr*NC2 + oc0 + 16] = f2bf(acc01[r] + bias1);
      }
      if (rr2 < M){
        ob[(size_t)rr2*NC2 + oc0]      = f2bf(acc10[r] + bias0);
        ob[(size_t)rr2*NC2 + oc0 + 16] = f2bf(acc11[r] + bias1);
      }
    } else {
      float* of = (float*)Out;
      if (rr < M){
        of[(size_t)rr*NC2 + oc0]      = acc00[r] + bias0;
        of[(size_t)rr*NC2 + oc0 + 16] = acc01[r] + bias1;
      }
      if (rr2 < M){
        of[(size_t)rr2*NC2 + oc0]      = acc10[r] + bias0;
        of[(size_t)rr2*NC2 + oc0 + 16] = acc11[r] + bias1;
      }
    }
  }
}

// ---------------- fused pool (sorted batch, binary search) + MLP head ----------------
__device__ __forceinline__ int lbound(const int* __restrict__ a, int n, int key){
  int lo = 0, hi = n;
  while (lo < hi){ int mid = (lo+hi) >> 1; if (a[mid] < key) lo = mid+1; else hi = mid; }
  return lo;
}

__global__ __launch_bounds__(128) void head_kernel(
    const float* __restrict__ h3, const int* __restrict__ ntype, const int* __restrict__ batch,
    const float* __restrict__ m1w, const float* __restrict__ m1b,
    const float* __restrict__ g1, const float* __restrict__ b1,
    const float* __restrict__ m2w, const float* __restrict__ m2b,
    const float* __restrict__ g2, const float* __restrict__ b2,
    const float* __restrict__ m3w, const float* __restrict__ m3b,
    float* __restrict__ out)
{
  __shared__ float p[128];
  __shared__ float hb[128];
  __shared__ float red[128];
  int b = blockIdx.x, j = threadIdx.x;
  int lo = lbound(batch, NN, b);
  int hi = lbound(batch, NN, b+1);
  // branchless masked pool, 4 rows in flight. Rows skipped by conv3 hold 0xAA
  // poison (finite ~-1.5e-13) -> masked to exact 0 by w=0 multiply.
  float s = 0.f, cnt = 0.f;
  int n = lo;
  for (; n + 3 < hi; n += 4){
    float w0 = (ntype[n]   == 0) ? 1.f : 0.f;
    float w1 = (ntype[n+1] == 0) ? 1.f : 0.f;
    float w2 = (ntype[n+2] == 0) ? 1.f : 0.f;
    float w3 = (ntype[n+3] == 0) ? 1.f : 0.f;
    s += w0*h3[(size_t)n*128 + j]     + w1*h3[(size_t)(n+1)*128 + j]
       + w2*h3[(size_t)(n+2)*128 + j] + w3*h3[(size_t)(n+3)*128 + j];
    cnt += w0 + w1 + w2 + w3;
  }
  for (; n < hi; ++n){
    float w = (ntype[n] == 0) ? 1.f : 0.f;
    s += w*h3[(size_t)n*128 + j];
    cnt += w;
  }
  p[j] = s / fmaxf(cnt, 1.f);
  __syncthreads();
  float a = m1b[j];
  for (int k=0; k<128; ++k) a += p[k]*m1w[k*128 + j];
  red[j] = a; __syncthreads();
  for (int off=64; off>0; off>>=1){ if (j<off) red[j] += red[j+off]; __syncthreads(); }
  float mu = red[0] * (1.f/128.f);
  __syncthreads();
  float d = a - mu;
  red[j] = d*d; __syncthreads();
  for (int off=64; off>0; off>>=1){ if (j<off) red[j] += red[j+off]; __syncthreads(); }
  float var = red[0] * (1.f/128.f);
  __syncthreads();
  hb[j] = lrelu(d * rsqrtf(var + 1e-5f) * g1[j] + b1[j]);
  __syncthreads();
  float a2 = 0.f;
  if (j < 64){
    a2 = m2b[j];
    for (int k=0; k<128; ++k) a2 += hb[k]*m2w[k*64 + j];
  }
  red[j] = (j<64) ? a2 : 0.f; __syncthreads();
  for (int off=64; off>0; off>>=1){ if (j<off) red[j] += red[j+off]; __syncthreads(); }
  float mu2 = red[0] * (1.f/64.f);
  __syncthreads();
  float d2 = a2 - mu2;
  red[j] = (j<64) ? d2*d2 : 0.f; __syncthreads();
  for (int off=64; off>0; off>>=1){ if (j<off) red[j] += red[j+off]; __syncthreads(); }
  float var2 = red[0] * (1.f/64.f);
  __syncthreads();
  if (j < 64) hb[j] = lrelu(d2 * rsqrtf(var2 + 1e-5f) * g2[j] + b2[j]);
  __syncthreads();
  if (j == 0){
    float o = m3b[0];
    for (int k=0; k<64; ++k) o += hb[k]*m3w[k];
    out[b] = o;
  }
}

extern "C" void kernel_launch(void* const* d_in, const int* in_sizes, int n_in,
                              void* d_out, int out_size, void* d_ws, size_t ws_size,
                              hipStream_t stream)
{
  const float* x        = (const float*)d_in[0];
  const int*   ntype    = (const int*)d_in[1];
  const int*   ei       = (const int*)d_in[2];
  const float* eattr    = (const float*)d_in[3];
  const int*   batch    = (const int*)d_in[4];
  const float* vp_w     = (const float*)d_in[5];
  const float* vp_b     = (const float*)d_in[6];
  const float* type_emb = (const float*)d_in[7];
  const float* c1_wl = (const float*)d_in[8];  const float* c1_bl = (const float*)d_in[9];
  const float* c1_wr = (const float*)d_in[10]; const float* c1_br = (const float*)d_in[11];
  const float* c1_we = (const float*)d_in[12]; const float* c1_att= (const float*)d_in[13];
  const float* c1_bias=(const float*)d_in[14];
  const float* c2_wl = (const float*)d_in[15]; const float* c2_bl = (const float*)d_in[16];
  const float* c2_wr = (const float*)d_in[17]; const float* c2_br = (const float*)d_in[18];
  const float* c2_we = (const float*)d_in[19]; const float* c2_att= (const float*)d_in[20];
  const float* c2_bias=(const float*)d_in[21];
  const float* c3_wl = (const float*)d_in[22]; const float* c3_bl = (const float*)d_in[23];
  const float* c3_wr = (const float*)d_in[24]; const float* c3_br = (const float*)d_in[25];
  const float* c3_we = (const float*)d_in[26]; const float* c3_att= (const float*)d_in[27];
  const float* c3_bias=(const float*)d_in[28];
  const float* m1_w = (const float*)d_in[29]; const float* m1_b = (const float*)d_in[30];
  const float* ln1_g= (const float*)d_in[31]; const float* ln1_b= (const float*)d_in[32];
  const float* m2_w = (const float*)d_in[33]; const float* m2_b = (const float*)d_in[34];
  const float* ln2_g= (const float*)d_in[35]; const float* ln2_b= (const float*)d_in[36];
  const float* m3_w = (const float*)d_in[37]; const float* m3_b = (const float*)d_in[38];
  const int* esrc = ei;
  const int* edst = ei + NE;
  float* outp = (float*)d_out;
  (void)in_sizes; (void)n_in; (void)out_size; (void)ws_size;

  // ---- workspace arena ----
  char* w = (char*)d_ws;
  auto alloc = [&](size_t bytes) -> void* {
    void* p = (void*)w;
    w += (bytes + 255) & ~(size_t)255;
    return p;
  };
  unsigned short* h1bf = (unsigned short*)alloc((size_t)NN*1024*2);  // conv1 out, bf16
  unsigned short* X2   = (unsigned short*)alloc((size_t)NN*512*2);   // [xl2 | xr2] bf16
  unsigned short* h2bf = (unsigned short*)alloc((size_t)NN*256*2);   // conv2 out, bf16
  float* X3   = (float*)alloc((size_t)NN*256*4);    // [xl3 | xr3] fp32
  float* h3   = (float*)alloc((size_t)NN*128*4);    // conv3 out (type0 rows only)
  unsigned short* W2lT = (unsigned short*)alloc((size_t)256*1024*2);
  unsigned short* W2rT = (unsigned short*)alloc((size_t)256*1024*2);
  unsigned short* W3lT = (unsigned short*)alloc((size_t)128*256*2);
  unsigned short* W3rT = (unsigned short*)alloc((size_t)128*256*2);
  float* Ul   = (float*)alloc(1024*4);
  float* CTl  = (float*)alloc(2048*4);
  float* Ur   = (float*)alloc(1024*4);
  float* CTr  = (float*)alloc(2048*4);
  const int zero_words = 3*NN + 2;                   // deg, rowctr, loop_sum, sync[2]
  float* zbase = (float*)alloc((size_t)zero_words*4);
  int*   deg      = (int*)zbase;
  int*   rowctr   = (int*)(zbase + NN);
  float* loop_sum = zbase + 2*NN;
  int*   sync_    = (int*)(zbase + 3*NN);
  float* loop_attr= (float*)alloc((size_t)NN*4);
  int*   rowptr   = (int*)alloc((size_t)(NN+1)*4);
  int*   srcs     = (int*)alloc((size_t)NE*4);
  float* eav      = (float*)alloc((size_t)NE*4);

  // ---- pipeline (8 dispatches) ----
  prep_kernel<<<180, 256, 0, stream>>>(vp_w, vp_b, type_emb,
      c1_wl, c1_bl, c1_wr, c1_br, Ul, CTl, Ur, CTr,
      c2_wl, c2_wr, c3_wl, c3_wr, W2lT, W2rT, W3lT, W3rT,
      zbase, zero_words);
  csr_kernel<<<(NE+1023)/1024, 1024, 0, stream>>>(esrc, edst, eattr,
      deg, loop_sum, rowptr, loop_attr, rowctr, srcs, eav, sync_);
  conv1_kernel<<<NN, 256, 0, stream>>>(rowptr, srcs, eav, loop_attr, x, ntype,
                                       Ul, CTl, Ur, CTr, c1_we, c1_att, c1_bias, h1bf);
  // c2: X2[10000,512] bf16, K=1024, NcH=256: cgrid=8, rgrid=157 -> 8*8*20=1280 blocks
  gemm_dual_mfma<true><<<1280, 256, 0, stream>>>(
      (const short*)h1bf, (const short*)W2lT, (const short*)W2rT, c2_bl, c2_br,
      (void*)X2, NN, 1024, 256, 8, 157);
  conv_kernel<2,64,4,false,true,true><<<NN, 64, 0, stream>>>(rowptr, srcs, eav, loop_attr, ntype,
      (const void*)X2, 512, 256, c2_we, c2_att, c2_bias, h2bf);
  // c3: X3[10000,256] fp32, K=256, NcH=128: cgrid=4, rgrid=157 -> 8*4*20=640 blocks
  gemm_dual_mfma<false><<<640, 256, 0, stream>>>(
      (const short*)h2bf, (const short*)W3lT, (const short*)W3rT, c3_bl, c3_br,
      (void*)X3, NN, 256, 128, 4, 157);
  conv_kernel<1,64,2,true,false,false><<<NN, 64, 0, stream>>>(rowptr, srcs, eav, loop_attr, ntype,
      (const void*)X3, 256, 128, c3_we, c3_att, c3_bias, h3);
  head_kernel<<<NBATCH, 128, 0, stream>>>(h3, ntype, batch, m1_w, m1_b, ln1_g, ln1_b,
                                          m2_w, m2_b, ln2_g, ln2_b, m3_w, m3_b, outp);
}

// Round 8
// 359.091 us; speedup vs baseline: 1.1526x; 1.1526x over previous
//
#include <hip/hip_runtime.h>
#include <math.h>

#define NN 10000
#define NE 100000
#define NBATCH 64

typedef short bf16x8 __attribute__((ext_vector_type(8)));
typedef float f32x4 __attribute__((ext_vector_type(4)));

__device__ __forceinline__ float lrelu(float v){ return v > 0.f ? v : 0.2f*v; }

// fp32 -> bf16 round-to-nearest-even
__device__ __forceinline__ unsigned short f2bf(float x){
  unsigned int u = __float_as_uint(x);
  u += 0x7fffu + ((u >> 16) & 1u);
  return (unsigned short)(u >> 16);
}
__device__ __forceinline__ float bf2f(unsigned short u){
  return __uint_as_float(((unsigned int)u) << 16);
}

// ---------------- prep: zero + c1 precompute + 4 weight transposes (fused) -------------
__global__ __launch_bounds__(256) void prep_kernel(
    const float* __restrict__ vp_w, const float* __restrict__ vp_b,
    const float* __restrict__ type_emb,
    const float* __restrict__ c1_wl, const float* __restrict__ c1_bl,
    const float* __restrict__ c1_wr, const float* __restrict__ c1_br,
    float* __restrict__ Ul, float* __restrict__ CTl,
    float* __restrict__ Ur, float* __restrict__ CTr,
    const float* __restrict__ c2_wl, const float* __restrict__ c2_wr,
    const float* __restrict__ c3_wl, const float* __restrict__ c3_wr,
    unsigned short* __restrict__ W2lT, unsigned short* __restrict__ W2rT,
    unsigned short* __restrict__ W3lT, unsigned short* __restrict__ W3rT,
    float* __restrict__ zbase, int zero_words)
{
  __shared__ float t[64][65];
  int b = blockIdx.x;
  int tid = threadIdx.x;
  if (b < 144){
    const float* in; unsigned short* out; int K, N, idx;
    if (b < 64)      { in=c2_wl; out=W2lT; K=1024; N=256; idx=b; }
    else if (b <128) { in=c2_wr; out=W2rT; K=1024; N=256; idx=b-64; }
    else if (b <136) { in=c3_wl; out=W3lT; K=256;  N=128; idx=b-128; }
    else             { in=c3_wr; out=W3rT; K=256;  N=128; idx=b-136; }
    int K64 = K >> 6;
    int kx = idx % K64, nx = idx / K64;
    int k0 = kx*64, n0 = nx*64;
    int lr = tid >> 4;
    int lc = (tid & 15) * 4;
#pragma unroll
    for (int i=0;i<4;++i){
      int r = lr + i*16;
      float4 v = *(const float4*)(in + (size_t)(k0+r)*N + n0 + lc);
      t[r][lc+0]=v.x; t[r][lc+1]=v.y; t[r][lc+2]=v.z; t[r][lc+3]=v.w;
    }
    __syncthreads();
    int sr = tid >> 3;
    int sc = (tid & 7) * 8;
#pragma unroll
    for (int i=0;i<2;++i){
      int n = sr + i*32;
      unsigned short tmp[8];
#pragma unroll
      for (int j=0;j<8;++j) tmp[j] = f2bf(t[sc+j][n]);
      unsigned short* op = out + (size_t)(n0+n)*K + k0 + sc;
      *(ushort4*)op       = make_ushort4(tmp[0],tmp[1],tmp[2],tmp[3]);
      *(ushort4*)(op + 4) = make_ushort4(tmp[4],tmp[5],tmp[6],tmp[7]);
    }
  } else if (b < 148){
    int j = (b-144)*256 + tid;
    float ul=0.f, c0l=0.f, c1l=0.f, ur=0.f, c0r=0.f, c1r=0.f;
    for (int k=0; k<128; ++k){
      float a = c1_wl[k*1024 + j], bb = c1_wr[k*1024 + j];
      float vw = vp_w[k], vb = vp_b[k], t0 = type_emb[k], t1 = type_emb[128+k];
      ul += vw*a; ur += vw*bb;
      c0l += (vb+t0)*a; c1l += (vb+t1)*a;
      c0r += (vb+t0)*bb; c1r += (vb+t1)*bb;
    }
    Ul[j]=ul; Ur[j]=ur;
    CTl[j]      = c0l + c1_bl[j];
    CTl[1024+j] = c1l + c1_bl[j];
    CTr[j]      = c0r + c1_br[j];
    CTr[1024+j] = c1r + c1_br[j];
  } else {
    for (int i = (b-148)*256 + tid; i < zero_words; i += 32*256)
      zbase[i] = 0.f;
  }
}

// ---------------- fused CSR build: count -> (last block) scan -> fill ----------------
__global__ __launch_bounds__(1024) void csr_kernel(
    const int* __restrict__ src, const int* __restrict__ dst, const float* __restrict__ ea,
    int* __restrict__ deg, float* __restrict__ loop_sum,
    int* __restrict__ rowptr, float* __restrict__ loop_attr,
    int* __restrict__ rowctr, int* __restrict__ srcs, float* __restrict__ eav,
    int* __restrict__ sync_)
{
  int tid = threadIdx.x;
  int e = blockIdx.x*1024 + tid;
  int d_ = 0; float eav_ = 0.f;
  bool active = e < NE;
  if (active){
    d_ = dst[e]; eav_ = ea[e];
    atomicAdd(&deg[d_], 1);
    atomicAdd(&loop_sum[d_], eav_);
  }
  __threadfence();
  __syncthreads();
  __shared__ int amlast;
  if (tid == 0) amlast = (atomicAdd(&sync_[0], 1) == (int)gridDim.x - 1);
  __syncthreads();
  if (amlast){
    __shared__ int wsum[16];
    __shared__ int carry_s;
    int lane = tid & 63, wid = tid >> 6;
    if (tid == 0) carry_s = 0;
    __syncthreads();
    for (int base = 0; base < NN; base += 1024){
      int i = base + tid;
      int v = 0; float ls = 0.f;
      if (i < NN){ v = atomicAdd(&deg[i], 0); ls = atomicAdd(&loop_sum[i], 0.f); }
      int incl = v;
#pragma unroll
      for (int off=1; off<64; off<<=1){
        int tt = __shfl_up(incl, off, 64);
        if (lane >= off) incl += tt;
      }
      if (lane == 63) wsum[wid] = incl;
      __syncthreads();
      int pre = carry_s;
      for (int w2=0; w2<wid; ++w2) pre += wsum[w2];
      if (i < NN){
        rowptr[i] = pre + incl - v;                          // exclusive scan
        loop_attr[i] = ls / fmaxf((float)v, 1.f);            // fill='mean'
      }
      __syncthreads();
      if (tid == 0){
        int t2 = 0;
        for (int w2=0; w2<16; ++w2) t2 += wsum[w2];
        carry_s += t2;
      }
      __syncthreads();
    }
    if (tid == 0) rowptr[NN] = carry_s;
    __threadfence();
    __syncthreads();
    if (tid == 0) atomicExch(&sync_[1], 1);
  }
  if (tid == 0){
    while (atomicAdd(&sync_[1], 0) == 0) __builtin_amdgcn_s_sleep(16);
  }
  __syncthreads();
  if (active){
    int p = atomicAdd(&rowptr[d_], 0) + atomicAdd(&rowctr[d_], 1);
    srcs[p] = src[e];
    eav[p] = eav_;
  }
}

// ---------------- conv1: fused GATv2, on-the-fly xl/xr, dual-stream softmax -----------
__global__ __launch_bounds__(256) void conv1_kernel(
    const int* __restrict__ rowptr, const int* __restrict__ srcs, const float* __restrict__ eav,
    const float* __restrict__ loop_attr, const float* __restrict__ x, const int* __restrict__ ntype,
    const float* __restrict__ Ul, const float* __restrict__ CTl,
    const float* __restrict__ Ur, const float* __restrict__ CTr,
    const float* __restrict__ we, const float* __restrict__ att, const float* __restrict__ bias,
    unsigned short* __restrict__ out)
{
  int n = blockIdx.x;
  int tid = threadIdx.x;
  int ch0 = tid * 4;
  float wev[4], atv[4], biv[4], ulv[4], c0l[4], c1l[4], xrv[4];
  {
    float urv[4], c0r[4], c1r[4];
#pragma unroll
    for (int v=0; v<4; ++v){
      int ch = ch0 + v;
      wev[v] = we[ch]; atv[v] = att[ch]; biv[v] = bias[ch];
      ulv[v] = Ul[ch]; c0l[v] = CTl[ch]; c1l[v] = CTl[1024+ch];
      urv[v] = Ur[ch]; c0r[v] = CTr[ch]; c1r[v] = CTr[1024+ch];
    }
    float xn = x[n];
    int tn = ntype[n];
#pragma unroll
    for (int v=0; v<4; ++v) xrv[v] = xn*urv[v] + (tn ? c1r[v] : c0r[v]);
  }
  float m0=-INFINITY, l0=0.f, A0[4]={0.f,0.f,0.f,0.f};
  float m1=-INFINITY, l1=0.f, A1[4]={0.f,0.f,0.f,0.f};
  int beg = rowptr[n], end = rowptr[n+1];
  for (int j = beg; j <= end; j += 2){     // index end = self-loop
    bool two = (j+1) <= end;
    int s0 = (j < end) ? srcs[j] : n;
    float e0 = (j < end) ? eav[j] : loop_attr[n];
    int s1 = n; float e1 = 0.f;
    if (two){ s1 = (j+1 < end) ? srcs[j+1] : n; e1 = (j+1 < end) ? eav[j+1] : loop_attr[n]; }
    float xs0 = x[s0]; int ts0 = ntype[s0];
    float xs1 = 0.f; int ts1 = 0;
    if (two){ xs1 = x[s1]; ts1 = ntype[s1]; }
    float xl0[4], xl1[4];
#pragma unroll
    for (int v=0; v<4; ++v){
      xl0[v] = xs0*ulv[v] + (ts0 ? c1l[v] : c0l[v]);
      xl1[v] = xs1*ulv[v] + (ts1 ? c1l[v] : c0l[v]);
    }
    float p0 = 0.f, p1 = 0.f;
#pragma unroll
    for (int v=0; v<4; ++v){
      p0 += atv[v]*lrelu(xl0[v] + xrv[v] + e0*wev[v]);
      p1 += atv[v]*lrelu(xl1[v] + xrv[v] + e1*wev[v]);
    }
#pragma unroll
    for (int mm=1; mm<32; mm<<=1){
      p0 += __shfl_xor(p0, mm, 64);
      p1 += __shfl_xor(p1, mm, 64);
    }
    {
      float mn = fmaxf(m0, p0), sc = __expf(m0-mn), pe = __expf(p0-mn);
      l0 = l0*sc + pe; m0 = mn;
#pragma unroll
      for (int v=0; v<4; ++v) A0[v] = A0[v]*sc + pe*xl0[v];
    }
    if (two){
      float mn = fmaxf(m1, p1), sc = __expf(m1-mn), pe = __expf(p1-mn);
      l1 = l1*sc + pe; m1 = mn;
#pragma unroll
      for (int v=0; v<4; ++v) A1[v] = A1[v]*sc + pe*xl1[v];
    }
  }
  float mn = fmaxf(m0, m1);
  float sc0 = __expf(m0-mn), sc1 = __expf(m1-mn);
  float inv = 1.f/(l0*sc0 + l1*sc1);
  size_t baseo = (size_t)n*1024 + ch0;
  ushort4 o;
  o.x = f2bf(lrelu((A0[0]*sc0 + A1[0]*sc1)*inv + biv[0]));
  o.y = f2bf(lrelu((A0[1]*sc0 + A1[1]*sc1)*inv + biv[1]));
  o.z = f2bf(lrelu((A0[2]*sc0 + A1[2]*sc1)*inv + biv[2]));
  o.w = f2bf(lrelu((A0[3]*sc0 + A1[3]*sc1)*inv + biv[3]));
  *(ushort4*)(out + baseo) = o;
}

// ---------------- generic fused GATv2 conv, dual-stream softmax ----------------
template<int H, int THREADS, int VPT, bool ONLY0, bool OUTBF, bool INBF>
__global__ __launch_bounds__(THREADS) void conv_kernel(
    const int* __restrict__ rowptr, const int* __restrict__ srcs, const float* __restrict__ eav,
    const float* __restrict__ loop_attr, const int* __restrict__ ntype,
    const void* __restrict__ Xv, int stride, int xr_off,
    const float* __restrict__ we, const float* __restrict__ att, const float* __restrict__ bias,
    void* __restrict__ out)
{
  const int HC = THREADS*VPT;
  const int TPH = THREADS/H;
  int n = blockIdx.x;
  if (ONLY0 && ntype[n] != 0) return;
  int tid = threadIdx.x;
  int ch0 = tid * VPT;
  const float* Xf = (const float*)Xv;
  const unsigned short* Xb = (const unsigned short*)Xv;
  float wev[VPT], atv[VPT], biv[VPT], xrv[VPT];
#pragma unroll
  for (int v=0; v<VPT; ++v){
    int ch = ch0+v;
    wev[v]=we[ch]; atv[v]=att[ch]; biv[v]=bias[ch];
  }
  if constexpr (INBF){
    ushort4 q = *(const ushort4*)(Xb + (size_t)n*stride + xr_off + ch0);
    xrv[0]=bf2f(q.x); xrv[1]=bf2f(q.y); xrv[2]=bf2f(q.z); xrv[3]=bf2f(q.w);
  } else {
#pragma unroll
    for (int v=0; v<VPT; ++v) xrv[v]=Xf[(size_t)n*stride + xr_off + ch0+v];
  }
  float m0=-INFINITY, l0=0.f, A0[VPT];
  float m1=-INFINITY, l1=0.f, A1[VPT];
#pragma unroll
  for (int v=0; v<VPT; ++v){ A0[v]=0.f; A1[v]=0.f; }
  int beg=rowptr[n], end=rowptr[n+1];
  for (int j=beg; j<=end; j+=2){
    bool two = (j+1) <= end;
    int s0 = (j < end) ? srcs[j] : n;
    float e0 = (j < end) ? eav[j] : loop_attr[n];
    int s1 = n; float e1 = 0.f;
    if (two){ s1 = (j+1 < end) ? srcs[j+1] : n; e1 = (j+1 < end) ? eav[j+1] : loop_attr[n]; }
    float x0[VPT], x1[VPT];
    if constexpr (INBF){
      ushort4 q0 = *(const ushort4*)(Xb + (size_t)s0*stride + ch0);
      x0[0]=bf2f(q0.x); x0[1]=bf2f(q0.y); x0[2]=bf2f(q0.z); x0[3]=bf2f(q0.w);
      if (two){
        ushort4 q1 = *(const ushort4*)(Xb + (size_t)s1*stride + ch0);
        x1[0]=bf2f(q1.x); x1[1]=bf2f(q1.y); x1[2]=bf2f(q1.z); x1[3]=bf2f(q1.w);
      } else { x1[0]=x1[1]=x1[2]=x1[3]=0.f; }
    } else if constexpr (VPT == 4){
      float4 q0 = *(const float4*)(Xf + (size_t)s0*stride + ch0);
      x0[0]=q0.x; x0[1]=q0.y; x0[2]=q0.z; x0[3]=q0.w;
      if (two){
        float4 q1 = *(const float4*)(Xf + (size_t)s1*stride + ch0);
        x1[0]=q1.x; x1[1]=q1.y; x1[2]=q1.z; x1[3]=q1.w;
      } else { x1[0]=x1[1]=x1[2]=x1[3]=0.f; }
    } else {
      float2 q0 = *(const float2*)(Xf + (size_t)s0*stride + ch0);
      x0[0]=q0.x; x0[1]=q0.y;
      if (two){
        float2 q1 = *(const float2*)(Xf + (size_t)s1*stride + ch0);
        x1[0]=q1.x; x1[1]=q1.y;
      } else { x1[0]=x1[1]=0.f; }
    }
    float p0=0.f, p1=0.f;
#pragma unroll
    for (int v=0; v<VPT; ++v){
      p0 += atv[v]*lrelu(x0[v]+xrv[v]+e0*wev[v]);
      p1 += atv[v]*lrelu(x1[v]+xrv[v]+e1*wev[v]);
    }
#pragma unroll
    for (int mm=1; mm<TPH; mm<<=1){
      p0 += __shfl_xor(p0, mm, 64);
      p1 += __shfl_xor(p1, mm, 64);
    }
    {
      float mn=fmaxf(m0,p0), sc=__expf(m0-mn), pe=__expf(p0-mn);
      l0=l0*sc+pe; m0=mn;
#pragma unroll
      for (int v=0; v<VPT; ++v) A0[v]=A0[v]*sc+pe*x0[v];
    }
    if (two){
      float mn=fmaxf(m1,p1), sc=__expf(m1-mn), pe=__expf(p1-mn);
      l1=l1*sc+pe; m1=mn;
#pragma unroll
      for (int v=0; v<VPT; ++v) A1[v]=A1[v]*sc+pe*x1[v];
    }
  }
  float mn = fmaxf(m0, m1);
  float sc0 = __expf(m0-mn), sc1 = __expf(m1-mn);
  float inv = 1.f/(l0*sc0 + l1*sc1);
  size_t baseo=(size_t)n*HC+ch0;
  if constexpr (OUTBF){
    unsigned short* ob = (unsigned short*)out;
    ushort4 o;
    o.x = f2bf(lrelu((A0[0]*sc0+A1[0]*sc1)*inv+biv[0]));
    o.y = f2bf(lrelu((A0[1]*sc0+A1[1]*sc1)*inv+biv[1]));
    o.z = f2bf(lrelu((A0[2]*sc0+A1[2]*sc1)*inv+biv[2]));
    o.w = f2bf(lrelu((A0[3]*sc0+A1[3]*sc1)*inv+biv[3]));
    *(ushort4*)(ob + baseo) = o;
  } else {
    float* of = (float*)out;
#pragma unroll
    for (int v=0; v<VPT; ++v) of[baseo+v]=lrelu((A0[v]*sc0+A1[v]*sc1)*inv+biv[v]);
  }
}

// ---------------- bf16 MFMA dual GEMM, LDS-staged via global_load_lds (m97 style) -----
// Out[M, 2*NcH] = [A@Wl + bl | A@Wr + br]; A[M][K] bf16, WT[NcH][K] bf16.
// Block tile 128x64, BK=64, 256 thr / 4 waves (2x2): wave tile 64x32 =
// 4x2 mfma_16x16x32 per 32-k step. Staging: 6 global_load_lds(16B)/thread/iter
// into 24KB LDS (A 16KB | B 8KB), XOR-swizzled (kchunk ^ (row&7)) so
// ds_read_b128 is 2-way-conflict-only (free) despite the DMA's fixed
// base+lane*16 layout. XCD swizzle keeps A strips L2-resident per XCD.
template<bool OUTBF>
__global__ __launch_bounds__(256) void gemm_dual_lds(
    const short* __restrict__ Abf,
    const short* __restrict__ WlT, const short* __restrict__ WrT,
    const float* __restrict__ bl, const float* __restrict__ br,
    void* __restrict__ Out, int M, int K, int NcH, int cgrid, int rgrid)
{
  __shared__ short lds[12288];    // A: [0,8192) shorts (128 rows x 64), B: [8192,12288)
  int id = blockIdx.x;
  int xcd = id & 7, slot = id >> 3;
  int nb = slot % cgrid;
  int rowgroup = (slot / cgrid) * 8 + xcd;
  if (rowgroup >= rgrid) return;
  int row0 = rowgroup * 128;
  int NC2 = 2*NcH;
  int halfx = NcH >> 6;
  int isR = nb >= halfx;
  const short* WT = isR ? WrT : WlT;
  const float* bias = isR ? br : bl;
  int col0 = (nb - (isR ? halfx : 0)) * 64;
  int gcol0 = nb * 64;
  int tid = threadIdx.x;
  int lane = tid & 63, wave = tid >> 6;
  int wm = wave >> 1, wn = wave & 1;
  int quad = lane >> 4, l16 = lane & 15;

  // staging source addresses (per-lane, swizzled); each wave stages its own
  // contiguous LDS range (wave-uniform base + lane*16).
  const short* asrc[4];
#pragma unroll
  for (int i=0;i<4;++i){
    int c = wave*256 + i*64 + lane;        // A chunk index 0..1023
    int m = c >> 3, j = c & 7;
    int gr = row0 + m; gr = gr < M ? gr : M-1;   // clamp; never stored
    asrc[i] = Abf + (size_t)gr*K + ((j ^ (m & 7)) << 3);
  }
  const short* bsrc[2];
#pragma unroll
  for (int i=0;i<2;++i){
    int c = wave*128 + i*64 + lane;        // B chunk index 0..511
    int nloc = c >> 3, j = c & 7;
    bsrc[i] = WT + (size_t)(col0 + nloc)*K + ((j ^ (nloc & 7)) << 3);
  }

  float biasv[2] = { bias[col0 + wn*32 + l16], bias[col0 + wn*32 + 16 + l16] };
  f32x4 acc[4][2];
#pragma unroll
  for (int f=0; f<4; ++f)
#pragma unroll
    for (int g=0; g<2; ++g) acc[f][g] = (f32x4){0.f,0.f,0.f,0.f};

  int niter = K >> 6;
  for (int it=0; it<niter; ++it){
    int k0 = it << 6;   // shorts
#pragma unroll
    for (int i=0;i<4;++i)
      __builtin_amdgcn_global_load_lds(asrc[i] + k0, &lds[(wave*256 + i*64)*8], 16, 0, 0);
#pragma unroll
    for (int i=0;i<2;++i)
      __builtin_amdgcn_global_load_lds(bsrc[i] + k0, &lds[8192 + (wave*128 + i*64)*8], 16, 0, 0);
    __syncthreads();   // drains DMA (vmcnt0) + makes LDS visible
#pragma unroll
    for (int s=0; s<2; ++s){
      int t = s*4 + quad;
      bf16x8 af[4], bfv[2];
#pragma unroll
      for (int f=0; f<4; ++f){
        int m = wm*64 + f*16 + l16;
        af[f] = *(const bf16x8*)&lds[m*64 + ((t ^ (m & 7)) << 3)];
      }
#pragma unroll
      for (int g=0; g<2; ++g){
        int nloc = wn*32 + g*16 + l16;
        bfv[g] = *(const bf16x8*)&lds[8192 + nloc*64 + ((t ^ (nloc & 7)) << 3)];
      }
#pragma unroll
      for (int f=0; f<4; ++f)
#pragma unroll
        for (int g=0; g<2; ++g)
          acc[f][g] = __builtin_amdgcn_mfma_f32_16x16x32_bf16(af[f], bfv[g], acc[f][g], 0,0,0);
    }
    __syncthreads();   // reads done before next overwrite
  }

#pragma unroll
  for (int f=0; f<4; ++f){
    int rbase = row0 + wm*64 + f*16 + quad*4;
#pragma unroll
    for (int r=0; r<4; ++r){
      int rr = rbase + r;
      if (rr < M){
#pragma unroll
        for (int g=0; g<2; ++g){
          int cc = gcol0 + wn*32 + g*16 + l16;
          float val = acc[f][g][r] + biasv[g];
          if constexpr (OUTBF) ((unsigned short*)Out)[(size_t)rr*NC2 + cc] = f2bf(val);
          else                 ((float*)Out)[(size_t)rr*NC2 + cc] = val;
        }
      }
    }
  }
}

// ---------------- fused pool (sorted batch, binary search) + MLP head ----------------
__device__ __forceinline__ int lbound(const int* __restrict__ a, int n, int key){
  int lo = 0, hi = n;
  while (lo < hi){ int mid = (lo+hi) >> 1; if (a[mid] < key) lo = mid+1; else hi = mid; }
  return lo;
}

__global__ __launch_bounds__(128) void head_kernel(
    const float* __restrict__ h3, const int* __restrict__ ntype, const int* __restrict__ batch,
    const float* __restrict__ m1w, const float* __restrict__ m1b,
    const float* __restrict__ g1, const float* __restrict__ b1,
    const float* __restrict__ m2w, const float* __restrict__ m2b,
    const float* __restrict__ g2, const float* __restrict__ b2,
    const float* __restrict__ m3w, const float* __restrict__ m3b,
    float* __restrict__ out)
{
  __shared__ float p[128];
  __shared__ float hb[128];
  __shared__ float red[128];
  int b = blockIdx.x, j = threadIdx.x;
  int lo = lbound(batch, NN, b);
  int hi = lbound(batch, NN, b+1);
  float s = 0.f, cnt = 0.f;
  int n = lo;
  for (; n + 3 < hi; n += 4){
    float w0 = (ntype[n]   == 0) ? 1.f : 0.f;
    float w1 = (ntype[n+1] == 0) ? 1.f : 0.f;
    float w2 = (ntype[n+2] == 0) ? 1.f : 0.f;
    float w3 = (ntype[n+3] == 0) ? 1.f : 0.f;
    s += w0*h3[(size_t)n*128 + j]     + w1*h3[(size_t)(n+1)*128 + j]
       + w2*h3[(size_t)(n+2)*128 + j] + w3*h3[(size_t)(n+3)*128 + j];
    cnt += w0 + w1 + w2 + w3;
  }
  for (; n < hi; ++n){
    float w = (ntype[n] == 0) ? 1.f : 0.f;
    s += w*h3[(size_t)n*128 + j];
    cnt += w;
  }
  p[j] = s / fmaxf(cnt, 1.f);
  __syncthreads();
  float a = m1b[j];
  for (int k=0; k<128; ++k) a += p[k]*m1w[k*128 + j];
  red[j] = a; __syncthreads();
  for (int off=64; off>0; off>>=1){ if (j<off) red[j] += red[j+off]; __syncthreads(); }
  float mu = red[0] * (1.f/128.f);
  __syncthreads();
  float d = a - mu;
  red[j] = d*d; __syncthreads();
  for (int off=64; off>0; off>>=1){ if (j<off) red[j] += red[j+off]; __syncthreads(); }
  float var = red[0] * (1.f/128.f);
  __syncthreads();
  hb[j] = lrelu(d * rsqrtf(var + 1e-5f) * g1[j] + b1[j]);
  __syncthreads();
  float a2 = 0.f;
  if (j < 64){
    a2 = m2b[j];
    for (int k=0; k<128; ++k) a2 += hb[k]*m2w[k*64 + j];
  }
  red[j] = (j<64) ? a2 : 0.f; __syncthreads();
  for (int off=64; off>0; off>>=1){ if (j<off) red[j] += red[j+off]; __syncthreads(); }
  float mu2 = red[0] * (1.f/64.f);
  __syncthreads();
  float d2 = a2 - mu2;
  red[j] = (j<64) ? d2*d2 : 0.f; __syncthreads();
  for (int off=64; off>0; off>>=1){ if (j<off) red[j] += red[j+off]; __syncthreads(); }
  float var2 = red[0] * (1.f/64.f);
  __syncthreads();
  if (j < 64) hb[j] = lrelu(d2 * rsqrtf(var2 + 1e-5f) * g2[j] + b2[j]);
  __syncthreads();
  if (j == 0){
    float o = m3b[0];
    for (int k=0; k<64; ++k) o += hb[k]*m3w[k];
    out[b] = o;
  }
}

extern "C" void kernel_launch(void* const* d_in, const int* in_sizes, int n_in,
                              void* d_out, int out_size, void* d_ws, size_t ws_size,
                              hipStream_t stream)
{
  const float* x        = (const float*)d_in[0];
  const int*   ntype    = (const int*)d_in[1];
  const int*   ei       = (const int*)d_in[2];
  const float* eattr    = (const float*)d_in[3];
  const int*   batch    = (const int*)d_in[4];
  const float* vp_w     = (const float*)d_in[5];
  const float* vp_b     = (const float*)d_in[6];
  const float* type_emb = (const float*)d_in[7];
  const float* c1_wl = (const float*)d_in[8];  const float* c1_bl = (const float*)d_in[9];
  const float* c1_wr = (const float*)d_in[10]; const float* c1_br = (const float*)d_in[11];
  const float* c1_we = (const float*)d_in[12]; const float* c1_att= (const float*)d_in[13];
  const float* c1_bias=(const float*)d_in[14];
  const float* c2_wl = (const float*)d_in[15]; const float* c2_bl = (const float*)d_in[16];
  const float* c2_wr = (const float*)d_in[17]; const float* c2_br = (const float*)d_in[18];
  const float* c2_we = (const float*)d_in[19]; const float* c2_att= (const float*)d_in[20];
  const float* c2_bias=(const float*)d_in[21];
  const float* c3_wl = (const float*)d_in[22]; const float* c3_bl = (const float*)d_in[23];
  const float* c3_wr = (const float*)d_in[24]; const float* c3_br = (const float*)d_in[25];
  const float* c3_we = (const float*)d_in[26]; const float* c3_att= (const float*)d_in[27];
  const float* c3_bias=(const float*)d_in[28];
  const float* m1_w = (const float*)d_in[29]; const float* m1_b = (const float*)d_in[30];
  const float* ln1_g= (const float*)d_in[31]; const float* ln1_b= (const float*)d_in[32];
  const float* m2_w = (const float*)d_in[33]; const float* m2_b = (const float*)d_in[34];
  const float* ln2_g= (const float*)d_in[35]; const float* ln2_b= (const float*)d_in[36];
  const float* m3_w = (const float*)d_in[37]; const float* m3_b = (const float*)d_in[38];
  const int* esrc = ei;
  const int* edst = ei + NE;
  float* outp = (float*)d_out;
  (void)in_sizes; (void)n_in; (void)out_size; (void)ws_size;

  // ---- workspace arena ----
  char* w = (char*)d_ws;
  auto alloc = [&](size_t bytes) -> void* {
    void* p = (void*)w;
    w += (bytes + 255) & ~(size_t)255;
    return p;
  };
  unsigned short* h1bf = (unsigned short*)alloc((size_t)NN*1024*2);  // conv1 out, bf16
  unsigned short* X2   = (unsigned short*)alloc((size_t)NN*512*2);   // [xl2 | xr2] bf16
  unsigned short* h2bf = (unsigned short*)alloc((size_t)NN*256*2);   // conv2 out, bf16
  float* X3   = (float*)alloc((size_t)NN*256*4);    // [xl3 | xr3] fp32
  float* h3   = (float*)alloc((size_t)NN*128*4);    // conv3 out (type0 rows only)
  unsigned short* W2lT = (unsigned short*)alloc((size_t)256*1024*2);
  unsigned short* W2rT = (unsigned short*)alloc((size_t)256*1024*2);
  unsigned short* W3lT = (unsigned short*)alloc((size_t)128*256*2);
  unsigned short* W3rT = (unsigned short*)alloc((size_t)128*256*2);
  float* Ul   = (float*)alloc(1024*4);
  float* CTl  = (float*)alloc(2048*4);
  float* Ur   = (float*)alloc(1024*4);
  float* CTr  = (float*)alloc(2048*4);
  const int zero_words = 3*NN + 2;                   // deg, rowctr, loop_sum, sync[2]
  float* zbase = (float*)alloc((size_t)zero_words*4);
  int*   deg      = (int*)zbase;
  int*   rowctr   = (int*)(zbase + NN);
  float* loop_sum = zbase + 2*NN;
  int*   sync_    = (int*)(zbase + 3*NN);
  float* loop_attr= (float*)alloc((size_t)NN*4);
  int*   rowptr   = (int*)alloc((size_t)(NN+1)*4);
  int*   srcs     = (int*)alloc((size_t)NE*4);
  float* eav      = (float*)alloc((size_t)NE*4);

  // ---- pipeline (8 dispatches) ----
  prep_kernel<<<180, 256, 0, stream>>>(vp_w, vp_b, type_emb,
      c1_wl, c1_bl, c1_wr, c1_br, Ul, CTl, Ur, CTr,
      c2_wl, c2_wr, c3_wl, c3_wr, W2lT, W2rT, W3lT, W3rT,
      zbase, zero_words);
  csr_kernel<<<(NE+1023)/1024, 1024, 0, stream>>>(esrc, edst, eattr,
      deg, loop_sum, rowptr, loop_attr, rowctr, srcs, eav, sync_);
  conv1_kernel<<<NN, 256, 0, stream>>>(rowptr, srcs, eav, loop_attr, x, ntype,
                                       Ul, CTl, Ur, CTr, c1_we, c1_att, c1_bias, h1bf);
  // c2: X2[10000,512] bf16, K=1024, NcH=256: cgrid=8, rgrid=ceil(10000/128)=79
  // -> 8*8*ceil(79/8)=640 blocks
  gemm_dual_lds<true><<<640, 256, 0, stream>>>(
      (const short*)h1bf, (const short*)W2lT, (const short*)W2rT, c2_bl, c2_br,
      (void*)X2, NN, 1024, 256, 8, 79);
  conv_kernel<2,64,4,false,true,true><<<NN, 64, 0, stream>>>(rowptr, srcs, eav, loop_attr, ntype,
      (const void*)X2, 512, 256, c2_we, c2_att, c2_bias, h2bf);
  // c3: X3[10000,256] fp32, K=256, NcH=128: cgrid=4, rgrid=79 -> 8*4*10=320 blocks
  gemm_dual_lds<false><<<320, 256, 0, stream>>>(
      (const short*)h2bf, (const short*)W3lT, (const short*)W3rT, c3_bl, c3_br,
      (void*)X3, NN, 256, 128, 4, 79);
  conv_kernel<1,64,2,true,false,false><<<NN, 64, 0, stream>>>(rowptr, srcs, eav, loop_attr, ntype,
      (const void*)X3, 256, 128, c3_we, c3_att, c3_bias, h3);
  head_kernel<<<NBATCH, 128, 0, stream>>>(h3, ntype, batch, m1_w, m1_b, ln1_g, ln1_b,
                                          m2_w, m2_b, ln2_g, ln2_b, m3_w, m3_b, outp);
}

// Round 9
// 347.378 us; speedup vs baseline: 1.1915x; 1.0337x over previous
//
#include <hip/hip_runtime.h>
#include <math.h>

#define NN 10000
#define NE 100000
#define E2 (NE + NN)
#define NBATCH 64

typedef short bf16x8 __attribute__((ext_vector_type(8)));
typedef float f32x4 __attribute__((ext_vector_type(4)));

__device__ __forceinline__ float lrelu(float v){ return v > 0.f ? v : 0.2f*v; }

// fp32 -> bf16 round-to-nearest-even
__device__ __forceinline__ unsigned short f2bf(float x){
  unsigned int u = __float_as_uint(x);
  u += 0x7fffu + ((u >> 16) & 1u);
  return (unsigned short)(u >> 16);
}
__device__ __forceinline__ float bf2f(unsigned short u){
  return __uint_as_float(((unsigned int)u) << 16);
}

// ---------------- prep: zero + c1 precompute (+CT2) + 4 weight transposes --------------
__global__ __launch_bounds__(256) void prep_kernel(
    const float* __restrict__ vp_w, const float* __restrict__ vp_b,
    const float* __restrict__ type_emb,
    const float* __restrict__ c1_wl, const float* __restrict__ c1_bl,
    const float* __restrict__ c1_wr, const float* __restrict__ c1_br,
    float* __restrict__ Ul, float* __restrict__ CTl,
    float* __restrict__ Ur, float* __restrict__ CT2,
    const float* __restrict__ c2_wl, const float* __restrict__ c2_wr,
    const float* __restrict__ c3_wl, const float* __restrict__ c3_wr,
    unsigned short* __restrict__ W2lT, unsigned short* __restrict__ W2rT,
    unsigned short* __restrict__ W3lT, unsigned short* __restrict__ W3rT,
    float* __restrict__ zbase, int zero_words)
{
  __shared__ float t[64][65];
  int b = blockIdx.x;
  int tid = threadIdx.x;
  if (b < 144){
    const float* in; unsigned short* out; int K, N, idx;
    if (b < 64)      { in=c2_wl; out=W2lT; K=1024; N=256; idx=b; }
    else if (b <128) { in=c2_wr; out=W2rT; K=1024; N=256; idx=b-64; }
    else if (b <136) { in=c3_wl; out=W3lT; K=256;  N=128; idx=b-128; }
    else             { in=c3_wr; out=W3rT; K=256;  N=128; idx=b-136; }
    int K64 = K >> 6;
    int kx = idx % K64, nx = idx / K64;
    int k0 = kx*64, n0 = nx*64;
    int lr = tid >> 4;
    int lc = (tid & 15) * 4;
#pragma unroll
    for (int i=0;i<4;++i){
      int r = lr + i*16;
      float4 v = *(const float4*)(in + (size_t)(k0+r)*N + n0 + lc);
      t[r][lc+0]=v.x; t[r][lc+1]=v.y; t[r][lc+2]=v.z; t[r][lc+3]=v.w;
    }
    __syncthreads();
    int sr = tid >> 3;
    int sc = (tid & 7) * 8;
#pragma unroll
    for (int i=0;i<2;++i){
      int n = sr + i*32;
      unsigned short tmp[8];
#pragma unroll
      for (int j=0;j<8;++j) tmp[j] = f2bf(t[sc+j][n]);
      unsigned short* op = out + (size_t)(n0+n)*K + k0 + sc;
      *(ushort4*)op       = make_ushort4(tmp[0],tmp[1],tmp[2],tmp[3]);
      *(ushort4*)(op + 4) = make_ushort4(tmp[4],tmp[5],tmp[6],tmp[7]);
    }
  } else if (b < 148){
    int j = (b-144)*256 + tid;
    float ul=0.f, c0l=0.f, c1l=0.f, ur=0.f, c0r=0.f, c1r=0.f;
    for (int k=0; k<128; ++k){
      float a = c1_wl[k*1024 + j], bb = c1_wr[k*1024 + j];
      float vw = vp_w[k], vb = vp_b[k], t0 = type_emb[k], t1 = type_emb[128+k];
      ul += vw*a; ur += vw*bb;
      c0l += (vb+t0)*a; c1l += (vb+t1)*a;
      c0r += (vb+t0)*bb; c1r += (vb+t1)*bb;
    }
    float bl = c1_bl[j], br = c1_br[j];
    Ul[j]=ul; Ur[j]=ur;
    CTl[j]      = c0l + bl;
    CTl[1024+j] = c1l + bl;
    // CT2[ts*2+tn] = CTl[ts] + CTr[tn] (both with their biases)
    CT2[j]        = (c0l+bl) + (c0r+br);
    CT2[1024+j]   = (c0l+bl) + (c1r+br);
    CT2[2048+j]   = (c1l+bl) + (c0r+br);
    CT2[3072+j]   = (c1l+bl) + (c1r+br);
  } else {
    for (int i = (b-148)*256 + tid; i < zero_words; i += 32*256)
      zbase[i] = 0.f;
  }
}

// ---------------- fused CSR build: count -> (last block) scan -> fill ----------------
__global__ __launch_bounds__(1024) void csr_kernel(
    const int* __restrict__ src, const int* __restrict__ dst, const float* __restrict__ ea,
    int* __restrict__ deg, float* __restrict__ loop_sum,
    int* __restrict__ rowptr, float* __restrict__ loop_attr,
    int* __restrict__ rowctr, int* __restrict__ srcs, int* __restrict__ dsts,
    float* __restrict__ eav, int* __restrict__ sync_)
{
  int tid = threadIdx.x;
  int e = blockIdx.x*1024 + tid;
  int d_ = 0; float eav_ = 0.f;
  bool active = e < NE;
  if (active){
    d_ = dst[e]; eav_ = ea[e];
    atomicAdd(&deg[d_], 1);
    atomicAdd(&loop_sum[d_], eav_);
  }
  __threadfence();
  __syncthreads();
  __shared__ int amlast;
  if (tid == 0) amlast = (atomicAdd(&sync_[0], 1) == (int)gridDim.x - 1);
  __syncthreads();
  if (amlast){
    __shared__ int wsum[16];
    __shared__ int carry_s;
    int lane = tid & 63, wid = tid >> 6;
    if (tid == 0) carry_s = 0;
    __syncthreads();
    for (int base = 0; base < NN; base += 1024){
      int i = base + tid;
      int v = 0; float ls = 0.f;
      if (i < NN){ v = atomicAdd(&deg[i], 0); ls = atomicAdd(&loop_sum[i], 0.f); }
      int incl = v;
#pragma unroll
      for (int off=1; off<64; off<<=1){
        int tt = __shfl_up(incl, off, 64);
        if (lane >= off) incl += tt;
      }
      if (lane == 63) wsum[wid] = incl;
      __syncthreads();
      int pre = carry_s;
      for (int w2=0; w2<wid; ++w2) pre += wsum[w2];
      if (i < NN){
        rowptr[i] = pre + incl - v;                          // exclusive scan
        loop_attr[i] = ls / fmaxf((float)v, 1.f);            // fill='mean'
      }
      __syncthreads();
      if (tid == 0){
        int t2 = 0;
        for (int w2=0; w2<16; ++w2) t2 += wsum[w2];
        carry_s += t2;
      }
      __syncthreads();
    }
    if (tid == 0) rowptr[NN] = carry_s;
    __threadfence();
    __syncthreads();
    if (tid == 0) atomicExch(&sync_[1], 1);
  }
  if (tid == 0){
    while (atomicAdd(&sync_[1], 0) == 0) __builtin_amdgcn_s_sleep(16);
  }
  __syncthreads();
  if (active){
    int p = atomicAdd(&rowptr[d_], 0) + atomicAdd(&rowctr[d_], 1);
    srcs[p] = src[e];
    dsts[p] = d_;
    eav[p] = eav_;
  }
}

// ---------------- conv1 pass 1: per-edge head scores (edge-parallel, no chain) --------
// slot j in [0,NE): CSR edge; j in [NE,E2): self-loop of node j-NE.
// 128 threads/edge (2 edges per 256-block), 8 ch/thread; CT2 in LDS (dyn type idx).
__global__ __launch_bounds__(256) void conv1_score(
    const int* __restrict__ srcs, const int* __restrict__ dsts, const float* __restrict__ eav,
    const float* __restrict__ loop_attr, const float* __restrict__ x, const int* __restrict__ ntype,
    const float* __restrict__ Ul, const float* __restrict__ Ur, const float* __restrict__ CT2,
    const float* __restrict__ we, const float* __restrict__ att,
    float* __restrict__ scores)
{
  __shared__ float ldsct[4096];
  int tid = threadIdx.x;
  for (int i = tid; i < 1024; i += 256)
    *(float4*)&ldsct[i*4] = *(const float4*)&CT2[i*4];
  int te = tid & 127;
  int sub = tid >> 7;
  int ch0 = te * 8;
  float ul[8], ur[8], wev[8], atv[8];
#pragma unroll
  for (int v=0; v<8; ++v){
    ul[v]=Ul[ch0+v]; ur[v]=Ur[ch0+v]; wev[v]=we[ch0+v]; atv[v]=att[ch0+v];
  }
  __syncthreads();
  for (int j = blockIdx.x*2 + sub; j < E2; j += gridDim.x*2){
    int s, d; float ea;
    if (j < NE){ s = srcs[j]; d = dsts[j]; ea = eav[j]; }
    else       { s = j - NE;  d = s;       ea = loop_attr[s]; }
    float xs = x[s], xn = x[d];
    int tt = ntype[s]*2 + ntype[d];
    const float* cp = &ldsct[tt*1024 + ch0];
    float4 c0 = *(const float4*)cp;
    float4 c1 = *(const float4*)(cp+4);
    float ct[8] = {c0.x,c0.y,c0.z,c0.w,c1.x,c1.y,c1.z,c1.w};
    float p = 0.f;
#pragma unroll
    for (int v=0; v<8; ++v){
      float z = fmaf(xs, ul[v], fmaf(xn, ur[v], fmaf(ea, wev[v], ct[v])));
      p += atv[v]*lrelu(z);
    }
#pragma unroll
    for (int mm=1; mm<16; mm<<=1) p += __shfl_xor(p, mm, 16);
    if ((te & 15) == 0) scores[(size_t)j*8 + (te>>4)] = p;
  }
}

// ---------------- conv1 pass 2: softmax + rank-3 aggregation + epilogue ----------------
// Block = 1 node, 256 thr = 8 head-groups x 32 lanes. Lane-local online softmax
// over its edges (deg/32, usually <=1), butterfly merge (m,l,S1,S20), then all
// threads write the 1024-ch epilogue: out = lrelu(S1*Ul + S20*CTl0 + (1-S20)*CTl1 + b).
__global__ __launch_bounds__(256) void conv1_agg(
    const int* __restrict__ rowptr, const int* __restrict__ srcs,
    const float* __restrict__ scores, const float* __restrict__ x, const int* __restrict__ ntype,
    const float* __restrict__ Ul, const float* __restrict__ CTl,
    const float* __restrict__ bias, unsigned short* __restrict__ out)
{
  int n = blockIdx.x;
  int tid = threadIdx.x;
  int h = tid >> 5, el = tid & 31;
  int beg = rowptr[n], deg = rowptr[n+1] - beg;
  int cnt = deg + 1;
  float m = -1e30f, l = 0.f, s1 = 0.f, s20 = 0.f;
  for (int i = el; i < cnt; i += 32){
    int pos; int s;
    if (i < deg){ pos = beg + i; s = srcs[pos]; }
    else        { pos = NE + n;  s = n; }
    float p = scores[(size_t)pos*8 + h];
    float xs = x[s];
    float w0 = (ntype[s] == 0) ? 1.f : 0.f;
    float mn = fmaxf(m, p), f = __expf(m-mn), pe = __expf(p-mn);
    l = l*f + pe; s1 = s1*f + pe*xs; s20 = s20*f + pe*w0; m = mn;
  }
#pragma unroll
  for (int off=1; off<32; off<<=1){
    float mb = __shfl_xor(m, off, 32), lb = __shfl_xor(l, off, 32);
    float s1b = __shfl_xor(s1, off, 32), s20b = __shfl_xor(s20, off, 32);
    float mn = fmaxf(m, mb), fa = __expf(m-mn), fb = __expf(mb-mn);
    l = l*fa + lb*fb; s1 = s1*fa + s1b*fb; s20 = s20*fa + s20b*fb; m = mn;
  }
  float inv = 1.f/l;
  s1 *= inv; s20 *= inv;
  float s21 = 1.f - s20;
  int ch0 = tid * 4;       // head of ch0..ch0+3 == tid>>5 == h
  float4 u  = *(const float4*)(Ul + ch0);
  float4 t0 = *(const float4*)(CTl + ch0);
  float4 t1 = *(const float4*)(CTl + 1024 + ch0);
  float4 bi = *(const float4*)(bias + ch0);
  ushort4 o;
  o.x = f2bf(lrelu(s1*u.x + s20*t0.x + s21*t1.x + bi.x));
  o.y = f2bf(lrelu(s1*u.y + s20*t0.y + s21*t1.y + bi.y));
  o.z = f2bf(lrelu(s1*u.z + s20*t0.z + s21*t1.z + bi.z));
  o.w = f2bf(lrelu(s1*u.w + s20*t0.w + s21*t1.w + bi.w));
  *(ushort4*)(out + (size_t)n*1024 + ch0) = o;
}

// ---------------- generic fused GATv2 conv, dual-stream softmax ----------------
template<int H, int THREADS, int VPT, bool ONLY0, bool OUTBF, bool INBF>
__global__ __launch_bounds__(THREADS) void conv_kernel(
    const int* __restrict__ rowptr, const int* __restrict__ srcs, const float* __restrict__ eav,
    const float* __restrict__ loop_attr, const int* __restrict__ ntype,
    const void* __restrict__ Xv, int stride, int xr_off,
    const float* __restrict__ we, const float* __restrict__ att, const float* __restrict__ bias,
    void* __restrict__ out)
{
  const int HC = THREADS*VPT;
  const int TPH = THREADS/H;
  int n = blockIdx.x;
  if (ONLY0 && ntype[n] != 0) return;
  int tid = threadIdx.x;
  int ch0 = tid * VPT;
  const float* Xf = (const float*)Xv;
  const unsigned short* Xb = (const unsigned short*)Xv;
  float wev[VPT], atv[VPT], biv[VPT], xrv[VPT];
#pragma unroll
  for (int v=0; v<VPT; ++v){
    int ch = ch0+v;
    wev[v]=we[ch]; atv[v]=att[ch]; biv[v]=bias[ch];
  }
  if constexpr (INBF){
    ushort4 q = *(const ushort4*)(Xb + (size_t)n*stride + xr_off + ch0);
    xrv[0]=bf2f(q.x); xrv[1]=bf2f(q.y); xrv[2]=bf2f(q.z); xrv[3]=bf2f(q.w);
  } else {
#pragma unroll
    for (int v=0; v<VPT; ++v) xrv[v]=Xf[(size_t)n*stride + xr_off + ch0+v];
  }
  float m0=-INFINITY, l0=0.f, A0[VPT];
  float m1=-INFINITY, l1=0.f, A1[VPT];
#pragma unroll
  for (int v=0; v<VPT; ++v){ A0[v]=0.f; A1[v]=0.f; }
  int beg=rowptr[n], end=rowptr[n+1];
  for (int j=beg; j<=end; j+=2){
    bool two = (j+1) <= end;
    int s0 = (j < end) ? srcs[j] : n;
    float e0 = (j < end) ? eav[j] : loop_attr[n];
    int s1 = n; float e1 = 0.f;
    if (two){ s1 = (j+1 < end) ? srcs[j+1] : n; e1 = (j+1 < end) ? eav[j+1] : loop_attr[n]; }
    float x0[VPT], x1[VPT];
    if constexpr (INBF){
      ushort4 q0 = *(const ushort4*)(Xb + (size_t)s0*stride + ch0);
      x0[0]=bf2f(q0.x); x0[1]=bf2f(q0.y); x0[2]=bf2f(q0.z); x0[3]=bf2f(q0.w);
      if (two){
        ushort4 q1 = *(const ushort4*)(Xb + (size_t)s1*stride + ch0);
        x1[0]=bf2f(q1.x); x1[1]=bf2f(q1.y); x1[2]=bf2f(q1.z); x1[3]=bf2f(q1.w);
      } else { x1[0]=x1[1]=x1[2]=x1[3]=0.f; }
    } else if constexpr (VPT == 4){
      float4 q0 = *(const float4*)(Xf + (size_t)s0*stride + ch0);
      x0[0]=q0.x; x0[1]=q0.y; x0[2]=q0.z; x0[3]=q0.w;
      if (two){
        float4 q1 = *(const float4*)(Xf + (size_t)s1*stride + ch0);
        x1[0]=q1.x; x1[1]=q1.y; x1[2]=q1.z; x1[3]=q1.w;
      } else { x1[0]=x1[1]=x1[2]=x1[3]=0.f; }
    } else {
      float2 q0 = *(const float2*)(Xf + (size_t)s0*stride + ch0);
      x0[0]=q0.x; x0[1]=q0.y;
      if (two){
        float2 q1 = *(const float2*)(Xf + (size_t)s1*stride + ch0);
        x1[0]=q1.x; x1[1]=q1.y;
      } else { x1[0]=x1[1]=0.f; }
    }
    float p0=0.f, p1=0.f;
#pragma unroll
    for (int v=0; v<VPT; ++v){
      p0 += atv[v]*lrelu(x0[v]+xrv[v]+e0*wev[v]);
      p1 += atv[v]*lrelu(x1[v]+xrv[v]+e1*wev[v]);
    }
#pragma unroll
    for (int mm=1; mm<TPH; mm<<=1){
      p0 += __shfl_xor(p0, mm, 64);
      p1 += __shfl_xor(p1, mm, 64);
    }
    {
      float mn=fmaxf(m0,p0), sc=__expf(m0-mn), pe=__expf(p0-mn);
      l0=l0*sc+pe; m0=mn;
#pragma unroll
      for (int v=0; v<VPT; ++v) A0[v]=A0[v]*sc+pe*x0[v];
    }
    if (two){
      float mn=fmaxf(m1,p1), sc=__expf(m1-mn), pe=__expf(p1-mn);
      l1=l1*sc+pe; m1=mn;
#pragma unroll
      for (int v=0; v<VPT; ++v) A1[v]=A1[v]*sc+pe*x1[v];
    }
  }
  float mn = fmaxf(m0, m1);
  float sc0 = __expf(m0-mn), sc1 = __expf(m1-mn);
  float inv = 1.f/(l0*sc0 + l1*sc1);
  size_t baseo=(size_t)n*HC+ch0;
  if constexpr (OUTBF){
    unsigned short* ob = (unsigned short*)out;
    ushort4 o;
    o.x = f2bf(lrelu((A0[0]*sc0+A1[0]*sc1)*inv+biv[0]));
    o.y = f2bf(lrelu((A0[1]*sc0+A1[1]*sc1)*inv+biv[1]));
    o.z = f2bf(lrelu((A0[2]*sc0+A1[2]*sc1)*inv+biv[2]));
    o.w = f2bf(lrelu((A0[3]*sc0+A1[3]*sc1)*inv+biv[3]));
    *(ushort4*)(ob + baseo) = o;
  } else {
    float* of = (float*)out;
#pragma unroll
    for (int v=0; v<VPT; ++v) of[baseo+v]=lrelu((A0[v]*sc0+A1[v]*sc1)*inv+biv[v]);
  }
}

// ---------------- bf16 MFMA dual GEMM, LDS-staged via global_load_lds (m97 style) -----
template<bool OUTBF>
__global__ __launch_bounds__(256) void gemm_dual_lds(
    const short* __restrict__ Abf,
    const short* __restrict__ WlT, const short* __restrict__ WrT,
    const float* __restrict__ bl, const float* __restrict__ br,
    void* __restrict__ Out, int M, int K, int NcH, int cgrid, int rgrid)
{
  __shared__ short lds[12288];    // A: [0,8192) shorts (128 rows x 64), B: [8192,12288)
  int id = blockIdx.x;
  int xcd = id & 7, slot = id >> 3;
  int nb = slot % cgrid;
  int rowgroup = (slot / cgrid) * 8 + xcd;
  if (rowgroup >= rgrid) return;
  int row0 = rowgroup * 128;
  int NC2 = 2*NcH;
  int halfx = NcH >> 6;
  int isR = nb >= halfx;
  const short* WT = isR ? WrT : WlT;
  const float* bias = isR ? br : bl;
  int col0 = (nb - (isR ? halfx : 0)) * 64;
  int gcol0 = nb * 64;
  int tid = threadIdx.x;
  int lane = tid & 63, wave = tid >> 6;
  int wm = wave >> 1, wn = wave & 1;
  int quad = lane >> 4, l16 = lane & 15;

  const short* asrc[4];
#pragma unroll
  for (int i=0;i<4;++i){
    int c = wave*256 + i*64 + lane;
    int m = c >> 3, j = c & 7;
    int gr = row0 + m; gr = gr < M ? gr : M-1;   // clamp; never stored
    asrc[i] = Abf + (size_t)gr*K + ((j ^ (m & 7)) << 3);
  }
  const short* bsrc[2];
#pragma unroll
  for (int i=0;i<2;++i){
    int c = wave*128 + i*64 + lane;
    int nloc = c >> 3, j = c & 7;
    bsrc[i] = WT + (size_t)(col0 + nloc)*K + ((j ^ (nloc & 7)) << 3);
  }

  float biasv[2] = { bias[col0 + wn*32 + l16], bias[col0 + wn*32 + 16 + l16] };
  f32x4 acc[4][2];
#pragma unroll
  for (int f=0; f<4; ++f)
#pragma unroll
    for (int g=0; g<2; ++g) acc[f][g] = (f32x4){0.f,0.f,0.f,0.f};

  int niter = K >> 6;
  for (int it=0; it<niter; ++it){
    int k0 = it << 6;
#pragma unroll
    for (int i=0;i<4;++i)
      __builtin_amdgcn_global_load_lds(asrc[i] + k0, &lds[(wave*256 + i*64)*8], 16, 0, 0);
#pragma unroll
    for (int i=0;i<2;++i)
      __builtin_amdgcn_global_load_lds(bsrc[i] + k0, &lds[8192 + (wave*128 + i*64)*8], 16, 0, 0);
    __syncthreads();
#pragma unroll
    for (int s=0; s<2; ++s){
      int t = s*4 + quad;
      bf16x8 af[4], bfv[2];
#pragma unroll
      for (int f=0; f<4; ++f){
        int m = wm*64 + f*16 + l16;
        af[f] = *(const bf16x8*)&lds[m*64 + ((t ^ (m & 7)) << 3)];
      }
#pragma unroll
      for (int g=0; g<2; ++g){
        int nloc = wn*32 + g*16 + l16;
        bfv[g] = *(const bf16x8*)&lds[8192 + nloc*64 + ((t ^ (nloc & 7)) << 3)];
      }
#pragma unroll
      for (int f=0; f<4; ++f)
#pragma unroll
        for (int g=0; g<2; ++g)
          acc[f][g] = __builtin_amdgcn_mfma_f32_16x16x32_bf16(af[f], bfv[g], acc[f][g], 0,0,0);
    }
    __syncthreads();
  }

#pragma unroll
  for (int f=0; f<4; ++f){
    int rbase = row0 + wm*64 + f*16 + quad*4;
#pragma unroll
    for (int r=0; r<4; ++r){
      int rr = rbase + r;
      if (rr < M){
#pragma unroll
        for (int g=0; g<2; ++g){
          int cc = gcol0 + wn*32 + g*16 + l16;
          float val = acc[f][g][r] + biasv[g];
          if constexpr (OUTBF) ((unsigned short*)Out)[(size_t)rr*NC2 + cc] = f2bf(val);
          else                 ((float*)Out)[(size_t)rr*NC2 + cc] = val;
        }
      }
    }
  }
}

// ---------------- fused pool (sorted batch, binary search) + MLP head ----------------
__device__ __forceinline__ int lbound(const int* __restrict__ a, int n, int key){
  int lo = 0, hi = n;
  while (lo < hi){ int mid = (lo+hi) >> 1; if (a[mid] < key) lo = mid+1; else hi = mid; }
  return lo;
}

__global__ __launch_bounds__(128) void head_kernel(
    const float* __restrict__ h3, const int* __restrict__ ntype, const int* __restrict__ batch,
    const float* __restrict__ m1w, const float* __restrict__ m1b,
    const float* __restrict__ g1, const float* __restrict__ b1,
    const float* __restrict__ m2w, const float* __restrict__ m2b,
    const float* __restrict__ g2, const float* __restrict__ b2,
    const float* __restrict__ m3w, const float* __restrict__ m3b,
    float* __restrict__ out)
{
  __shared__ float p[128];
  __shared__ float hb[128];
  __shared__ float red[128];
  int b = blockIdx.x, j = threadIdx.x;
  int lo = lbound(batch, NN, b);
  int hi = lbound(batch, NN, b+1);
  float s = 0.f, cnt = 0.f;
  int n = lo;
  for (; n + 3 < hi; n += 4){
    float w0 = (ntype[n]   == 0) ? 1.f : 0.f;
    float w1 = (ntype[n+1] == 0) ? 1.f : 0.f;
    float w2 = (ntype[n+2] == 0) ? 1.f : 0.f;
    float w3 = (ntype[n+3] == 0) ? 1.f : 0.f;
    s += w0*h3[(size_t)n*128 + j]     + w1*h3[(size_t)(n+1)*128 + j]
       + w2*h3[(size_t)(n+2)*128 + j] + w3*h3[(size_t)(n+3)*128 + j];
    cnt += w0 + w1 + w2 + w3;
  }
  for (; n < hi; ++n){
    float w = (ntype[n] == 0) ? 1.f : 0.f;
    s += w*h3[(size_t)n*128 + j];
    cnt += w;
  }
  p[j] = s / fmaxf(cnt, 1.f);
  __syncthreads();
  float a = m1b[j];
  for (int k=0; k<128; ++k) a += p[k]*m1w[k*128 + j];
  red[j] = a; __syncthreads();
  for (int off=64; off>0; off>>=1){ if (j<off) red[j] += red[j+off]; __syncthreads(); }
  float mu = red[0] * (1.f/128.f);
  __syncthreads();
  float d = a - mu;
  red[j] = d*d; __syncthreads();
  for (int off=64; off>0; off>>=1){ if (j<off) red[j] += red[j+off]; __syncthreads(); }
  float var = red[0] * (1.f/128.f);
  __syncthreads();
  hb[j] = lrelu(d * rsqrtf(var + 1e-5f) * g1[j] + b1[j]);
  __syncthreads();
  float a2 = 0.f;
  if (j < 64){
    a2 = m2b[j];
    for (int k=0; k<128; ++k) a2 += hb[k]*m2w[k*64 + j];
  }
  red[j] = (j<64) ? a2 : 0.f; __syncthreads();
  for (int off=64; off>0; off>>=1){ if (j<off) red[j] += red[j+off]; __syncthreads(); }
  float mu2 = red[0] * (1.f/64.f);
  __syncthreads();
  float d2 = a2 - mu2;
  red[j] = (j<64) ? d2*d2 : 0.f; __syncthreads();
  for (int off=64; off>0; off>>=1){ if (j<off) red[j] += red[j+off]; __syncthreads(); }
  float var2 = red[0] * (1.f/64.f);
  __syncthreads();
  if (j < 64) hb[j] = lrelu(d2 * rsqrtf(var2 + 1e-5f) * g2[j] + b2[j]);
  __syncthreads();
  if (j == 0){
    float o = m3b[0];
    for (int k=0; k<64; ++k) o += hb[k]*m3w[k];
    out[b] = o;
  }
}

extern "C" void kernel_launch(void* const* d_in, const int* in_sizes, int n_in,
                              void* d_out, int out_size, void* d_ws, size_t ws_size,
                              hipStream_t stream)
{
  const float* x        = (const float*)d_in[0];
  const int*   ntype    = (const int*)d_in[1];
  const int*   ei       = (const int*)d_in[2];
  const float* eattr    = (const float*)d_in[3];
  const int*   batch    = (const int*)d_in[4];
  const float* vp_w     = (const float*)d_in[5];
  const float* vp_b     = (const float*)d_in[6];
  const float* type_emb = (const float*)d_in[7];
  const float* c1_wl = (const float*)d_in[8];  const float* c1_bl = (const float*)d_in[9];
  const float* c1_wr = (const float*)d_in[10]; const float* c1_br = (const float*)d_in[11];
  const float* c1_we = (const float*)d_in[12]; const float* c1_att= (const float*)d_in[13];
  const float* c1_bias=(const float*)d_in[14];
  const float* c2_wl = (const float*)d_in[15]; const float* c2_bl = (const float*)d_in[16];
  const float* c2_wr = (const float*)d_in[17]; const float* c2_br = (const float*)d_in[18];
  const float* c2_we = (const float*)d_in[19]; const float* c2_att= (const float*)d_in[20];
  const float* c2_bias=(const float*)d_in[21];
  const float* c3_wl = (const float*)d_in[22]; const float* c3_bl = (const float*)d_in[23];
  const float* c3_wr = (const float*)d_in[24]; const float* c3_br = (const float*)d_in[25];
  const float* c3_we = (const float*)d_in[26]; const float* c3_att= (const float*)d_in[27];
  const float* c3_bias=(const float*)d_in[28];
  const float* m1_w = (const float*)d_in[29]; const float* m1_b = (const float*)d_in[30];
  const float* ln1_g= (const float*)d_in[31]; const float* ln1_b= (const float*)d_in[32];
  const float* m2_w = (const float*)d_in[33]; const float* m2_b = (const float*)d_in[34];
  const float* ln2_g= (const float*)d_in[35]; const float* ln2_b= (const float*)d_in[36];
  const float* m3_w = (const float*)d_in[37]; const float* m3_b = (const float*)d_in[38];
  const int* esrc = ei;
  const int* edst = ei + NE;
  float* outp = (float*)d_out;
  (void)in_sizes; (void)n_in; (void)out_size; (void)ws_size;

  // ---- workspace arena ----
  char* w = (char*)d_ws;
  auto alloc = [&](size_t bytes) -> void* {
    void* p = (void*)w;
    w += (bytes + 255) & ~(size_t)255;
    return p;
  };
  unsigned short* h1bf = (unsigned short*)alloc((size_t)NN*1024*2);  // conv1 out, bf16
  unsigned short* X2   = (unsigned short*)alloc((size_t)NN*512*2);   // [xl2 | xr2] bf16
  unsigned short* h2bf = (unsigned short*)alloc((size_t)NN*256*2);   // conv2 out, bf16
  float* X3   = (float*)alloc((size_t)NN*256*4);    // [xl3 | xr3] fp32
  float* h3   = (float*)alloc((size_t)NN*128*4);    // conv3 out (type0 rows only)
  unsigned short* W2lT = (unsigned short*)alloc((size_t)256*1024*2);
  unsigned short* W2rT = (unsigned short*)alloc((size_t)256*1024*2);
  unsigned short* W3lT = (unsigned short*)alloc((size_t)128*256*2);
  unsigned short* W3rT = (unsigned short*)alloc((size_t)128*256*2);
  float* Ul   = (float*)alloc(1024*4);
  float* CTl  = (float*)alloc(2048*4);
  float* Ur   = (float*)alloc(1024*4);
  float* CT2  = (float*)alloc(4096*4);
  float* scores = (float*)alloc((size_t)E2*8*4);
  const int zero_words = 3*NN + 2;                   // deg, rowctr, loop_sum, sync[2]
  float* zbase = (float*)alloc((size_t)zero_words*4);
  int*   deg      = (int*)zbase;
  int*   rowctr   = (int*)(zbase + NN);
  float* loop_sum = zbase + 2*NN;
  int*   sync_    = (int*)(zbase + 3*NN);
  float* loop_attr= (float*)alloc((size_t)NN*4);
  int*   rowptr   = (int*)alloc((size_t)(NN+1)*4);
  int*   srcs     = (int*)alloc((size_t)NE*4);
  int*   dsts     = (int*)alloc((size_t)NE*4);
  float* eav      = (float*)alloc((size_t)NE*4);

  // ---- pipeline (9 dispatches) ----
  prep_kernel<<<180, 256, 0, stream>>>(vp_w, vp_b, type_emb,
      c1_wl, c1_bl, c1_wr, c1_br, Ul, CTl, Ur, CT2,
      c2_wl, c2_wr, c3_wl, c3_wr, W2lT, W2rT, W3lT, W3rT,
      zbase, zero_words);
  csr_kernel<<<(NE+1023)/1024, 1024, 0, stream>>>(esrc, edst, eattr,
      deg, loop_sum, rowptr, loop_attr, rowctr, srcs, dsts, eav, sync_);
  conv1_score<<<2048, 256, 0, stream>>>(srcs, dsts, eav, loop_attr, x, ntype,
      Ul, Ur, CT2, c1_we, c1_att, scores);
  conv1_agg<<<NN, 256, 0, stream>>>(rowptr, srcs, scores, x, ntype,
      Ul, CTl, c1_bias, h1bf);
  // c2: X2[10000,512] bf16, K=1024, NcH=256: cgrid=8, rgrid=79 -> 640 blocks
  gemm_dual_lds<true><<<640, 256, 0, stream>>>(
      (const short*)h1bf, (const short*)W2lT, (const short*)W2rT, c2_bl, c2_br,
      (void*)X2, NN, 1024, 256, 8, 79);
  conv_kernel<2,64,4,false,true,true><<<NN, 64, 0, stream>>>(rowptr, srcs, eav, loop_attr, ntype,
      (const void*)X2, 512, 256, c2_we, c2_att, c2_bias, h2bf);
  // c3: X3[10000,256] fp32, K=256, NcH=128: cgrid=4, rgrid=79 -> 320 blocks
  gemm_dual_lds<false><<<320, 256, 0, stream>>>(
      (const short*)h2bf, (const short*)W3lT, (const short*)W3rT, c3_bl, c3_br,
      (void*)X3, NN, 256, 128, 4, 79);
  conv_kernel<1,64,2,true,false,false><<<NN, 64, 0, stream>>>(rowptr, srcs, eav, loop_attr, ntype,
      (const void*)X3, 256, 128, c3_we, c3_att, c3_bias, h3);
  head_kernel<<<NBATCH, 128, 0, stream>>>(h3, ntype, batch, m1_w, m1_b, ln1_g, ln1_b,
                                          m2_w, m2_b, ln2_g, ln2_b, m3_w, m3_b, outp);
}

// Round 10
// 326.634 us; speedup vs baseline: 1.2672x; 1.0635x over previous
//
#include <hip/hip_runtime.h>
#include <math.h>

#define NN 10000
#define NE 100000
#define E2 (NE + NN)
#define NBATCH 64

typedef short bf16x8 __attribute__((ext_vector_type(8)));
typedef float f32x4 __attribute__((ext_vector_type(4)));

__device__ __forceinline__ float lrelu(float v){ return v > 0.f ? v : 0.2f*v; }

// fp32 -> bf16 round-to-nearest-even
__device__ __forceinline__ unsigned short f2bf(float x){
  unsigned int u = __float_as_uint(x);
  u += 0x7fffu + ((u >> 16) & 1u);
  return (unsigned short)(u >> 16);
}
__device__ __forceinline__ float bf2f(unsigned short u){
  return __uint_as_float(((unsigned int)u) << 16);
}

// ---------------- prep: zero + c1 precompute (+CT2) + 4 weight transposes --------------
__global__ __launch_bounds__(256) void prep_kernel(
    const float* __restrict__ vp_w, const float* __restrict__ vp_b,
    const float* __restrict__ type_emb,
    const float* __restrict__ c1_wl, const float* __restrict__ c1_bl,
    const float* __restrict__ c1_wr, const float* __restrict__ c1_br,
    float* __restrict__ Ul, float* __restrict__ CTl,
    float* __restrict__ Ur, float* __restrict__ CT2,
    const float* __restrict__ c2_wl, const float* __restrict__ c2_wr,
    const float* __restrict__ c3_wl, const float* __restrict__ c3_wr,
    unsigned short* __restrict__ W2lT, unsigned short* __restrict__ W2rT,
    unsigned short* __restrict__ W3lT, unsigned short* __restrict__ W3rT,
    float* __restrict__ zbase, int zero_words)
{
  __shared__ float t[64][65];
  int b = blockIdx.x;
  int tid = threadIdx.x;
  if (b < 144){
    const float* in; unsigned short* out; int K, N, idx;
    if (b < 64)      { in=c2_wl; out=W2lT; K=1024; N=256; idx=b; }
    else if (b <128) { in=c2_wr; out=W2rT; K=1024; N=256; idx=b-64; }
    else if (b <136) { in=c3_wl; out=W3lT; K=256;  N=128; idx=b-128; }
    else             { in=c3_wr; out=W3rT; K=256;  N=128; idx=b-136; }
    int K64 = K >> 6;
    int kx = idx % K64, nx = idx / K64;
    int k0 = kx*64, n0 = nx*64;
    int lr = tid >> 4;
    int lc = (tid & 15) * 4;
#pragma unroll
    for (int i=0;i<4;++i){
      int r = lr + i*16;
      float4 v = *(const float4*)(in + (size_t)(k0+r)*N + n0 + lc);
      t[r][lc+0]=v.x; t[r][lc+1]=v.y; t[r][lc+2]=v.z; t[r][lc+3]=v.w;
    }
    __syncthreads();
    int sr = tid >> 3;
    int sc = (tid & 7) * 8;
#pragma unroll
    for (int i=0;i<2;++i){
      int n = sr + i*32;
      unsigned short tmp[8];
#pragma unroll
      for (int j=0;j<8;++j) tmp[j] = f2bf(t[sc+j][n]);
      unsigned short* op = out + (size_t)(n0+n)*K + k0 + sc;
      *(ushort4*)op       = make_ushort4(tmp[0],tmp[1],tmp[2],tmp[3]);
      *(ushort4*)(op + 4) = make_ushort4(tmp[4],tmp[5],tmp[6],tmp[7]);
    }
  } else if (b < 148){
    int j = (b-144)*256 + tid;
    float ul=0.f, c0l=0.f, c1l=0.f, ur=0.f, c0r=0.f, c1r=0.f;
    for (int k=0; k<128; ++k){
      float a = c1_wl[k*1024 + j], bb = c1_wr[k*1024 + j];
      float vw = vp_w[k], vb = vp_b[k], t0 = type_emb[k], t1 = type_emb[128+k];
      ul += vw*a; ur += vw*bb;
      c0l += (vb+t0)*a; c1l += (vb+t1)*a;
      c0r += (vb+t0)*bb; c1r += (vb+t1)*bb;
    }
    float bl = c1_bl[j], br = c1_br[j];
    Ul[j]=ul; Ur[j]=ur;
    CTl[j]      = c0l + bl;
    CTl[1024+j] = c1l + bl;
    // CT2[ts*2+tn] = CTl[ts] + CTr[tn] (both with their biases)
    CT2[j]        = (c0l+bl) + (c0r+br);
    CT2[1024+j]   = (c0l+bl) + (c1r+br);
    CT2[2048+j]   = (c1l+bl) + (c0r+br);
    CT2[3072+j]   = (c1l+bl) + (c1r+br);
  } else {
    for (int i = (b-148)*256 + tid; i < zero_words; i += 32*256)
      zbase[i] = 0.f;
  }
}

// ---------------- CSR build: 3 kernels (count -> scan -> fill), no spin-waits ----------
__global__ void count_kernel(const int* __restrict__ dst, const float* __restrict__ ea,
                             int* __restrict__ deg, float* __restrict__ loop_sum){
  int e = blockIdx.x*256 + threadIdx.x;
  if (e < NE){
    int d = dst[e];
    atomicAdd(&deg[d], 1);
    atomicAdd(&loop_sum[d], ea[e]);
  }
}

__global__ __launch_bounds__(1024) void scan_kernel(const int* __restrict__ deg,
    const float* __restrict__ loop_sum, int* __restrict__ rowptr, float* __restrict__ loop_attr){
  __shared__ int wsum[16];
  __shared__ int carry_s;
  int tid = threadIdx.x;
  int lane = tid & 63, wid = tid >> 6;
  if (tid == 0) carry_s = 0;
  __syncthreads();
  for (int base = 0; base < NN; base += 1024){
    int i = base + tid;
    int v = (i < NN) ? deg[i] : 0;
    int incl = v;
#pragma unroll
    for (int off = 1; off < 64; off <<= 1){
      int t = __shfl_up(incl, off, 64);
      if (lane >= off) incl += t;
    }
    if (lane == 63) wsum[wid] = incl;
    __syncthreads();
    int pre = carry_s;
    for (int w = 0; w < wid; ++w) pre += wsum[w];
    if (i < NN){
      rowptr[i] = pre + incl - v;                           // exclusive scan
      loop_attr[i] = loop_sum[i] / fmaxf((float)v, 1.f);    // fill='mean'
    }
    __syncthreads();
    if (tid == 0){
      int t = 0;
      for (int w = 0; w < 16; ++w) t += wsum[w];
      carry_s += t;
    }
    __syncthreads();
  }
  if (tid == 0) rowptr[NN] = carry_s;
}

__global__ void fill_kernel(const int* __restrict__ src, const int* __restrict__ dst,
                            const float* __restrict__ ea, const int* __restrict__ rowptr,
                            int* __restrict__ rowctr, int* __restrict__ srcs,
                            int* __restrict__ dsts, float* __restrict__ eav){
  int e = blockIdx.x*256 + threadIdx.x;
  if (e < NE){
    int d = dst[e];
    int p = rowptr[d] + atomicAdd(&rowctr[d], 1);
    srcs[p] = src[e];
    dsts[p] = d;
    eav[p] = ea[e];
  }
}

// ---------------- conv1 pass 1: per-edge head scores (edge-parallel, no chain) --------
// slot j in [0,NE): CSR edge; j in [NE,E2): self-loop of node j-NE.
// 128 threads/edge (2 edges per 256-block), 8 ch/thread; CT2 in LDS (dyn type idx).
__global__ __launch_bounds__(256) void conv1_score(
    const int* __restrict__ srcs, const int* __restrict__ dsts, const float* __restrict__ eav,
    const float* __restrict__ loop_attr, const float* __restrict__ x, const int* __restrict__ ntype,
    const float* __restrict__ Ul, const float* __restrict__ Ur, const float* __restrict__ CT2,
    const float* __restrict__ we, const float* __restrict__ att,
    float* __restrict__ scores)
{
  __shared__ float ldsct[4096];
  int tid = threadIdx.x;
  for (int i = tid; i < 1024; i += 256)
    *(float4*)&ldsct[i*4] = *(const float4*)&CT2[i*4];
  int te = tid & 127;
  int sub = tid >> 7;
  int ch0 = te * 8;
  float ul[8], ur[8], wev[8], atv[8];
#pragma unroll
  for (int v=0; v<8; ++v){
    ul[v]=Ul[ch0+v]; ur[v]=Ur[ch0+v]; wev[v]=we[ch0+v]; atv[v]=att[ch0+v];
  }
  __syncthreads();
  for (int j = blockIdx.x*2 + sub; j < E2; j += gridDim.x*2){
    int s, d; float ea;
    if (j < NE){ s = srcs[j]; d = dsts[j]; ea = eav[j]; }
    else       { s = j - NE;  d = s;       ea = loop_attr[s]; }
    float xs = x[s], xn = x[d];
    int tt = ntype[s]*2 + ntype[d];
    const float* cp = &ldsct[tt*1024 + ch0];
    float4 c0 = *(const float4*)cp;
    float4 c1 = *(const float4*)(cp+4);
    float ct[8] = {c0.x,c0.y,c0.z,c0.w,c1.x,c1.y,c1.z,c1.w};
    float p = 0.f;
#pragma unroll
    for (int v=0; v<8; ++v){
      float z = fmaf(xs, ul[v], fmaf(xn, ur[v], fmaf(ea, wev[v], ct[v])));
      p += atv[v]*lrelu(z);
    }
#pragma unroll
    for (int mm=1; mm<16; mm<<=1) p += __shfl_xor(p, mm, 16);
    if ((te & 15) == 0) scores[(size_t)j*8 + (te>>4)] = p;
  }
}

// ---------------- conv1 pass 2: softmax + rank-3 aggregation + epilogue ----------------
__global__ __launch_bounds__(256) void conv1_agg(
    const int* __restrict__ rowptr, const int* __restrict__ srcs,
    const float* __restrict__ scores, const float* __restrict__ x, const int* __restrict__ ntype,
    const float* __restrict__ Ul, const float* __restrict__ CTl,
    const float* __restrict__ bias, unsigned short* __restrict__ out)
{
  int n = blockIdx.x;
  int tid = threadIdx.x;
  int h = tid >> 5, el = tid & 31;
  int beg = rowptr[n], deg = rowptr[n+1] - beg;
  int cnt = deg + 1;
  float m = -1e30f, l = 0.f, s1 = 0.f, s20 = 0.f;
  for (int i = el; i < cnt; i += 32){
    int pos; int s;
    if (i < deg){ pos = beg + i; s = srcs[pos]; }
    else        { pos = NE + n;  s = n; }
    float p = scores[(size_t)pos*8 + h];
    float xs = x[s];
    float w0 = (ntype[s] == 0) ? 1.f : 0.f;
    float mn = fmaxf(m, p), f = __expf(m-mn), pe = __expf(p-mn);
    l = l*f + pe; s1 = s1*f + pe*xs; s20 = s20*f + pe*w0; m = mn;
  }
#pragma unroll
  for (int off=1; off<32; off<<=1){
    float mb = __shfl_xor(m, off, 32), lb = __shfl_xor(l, off, 32);
    float s1b = __shfl_xor(s1, off, 32), s20b = __shfl_xor(s20, off, 32);
    float mn = fmaxf(m, mb), fa = __expf(m-mn), fb = __expf(mb-mn);
    l = l*fa + lb*fb; s1 = s1*fa + s1b*fb; s20 = s20*fa + s20b*fb; m = mn;
  }
  float inv = 1.f/l;
  s1 *= inv; s20 *= inv;
  float s21 = 1.f - s20;
  int ch0 = tid * 4;       // head of ch0..ch0+3 == tid>>5 == h
  float4 u  = *(const float4*)(Ul + ch0);
  float4 t0 = *(const float4*)(CTl + ch0);
  float4 t1 = *(const float4*)(CTl + 1024 + ch0);
  float4 bi = *(const float4*)(bias + ch0);
  ushort4 o;
  o.x = f2bf(lrelu(s1*u.x + s20*t0.x + s21*t1.x + bi.x));
  o.y = f2bf(lrelu(s1*u.y + s20*t0.y + s21*t1.y + bi.y));
  o.z = f2bf(lrelu(s1*u.z + s20*t0.z + s21*t1.z + bi.z));
  o.w = f2bf(lrelu(s1*u.w + s20*t0.w + s21*t1.w + bi.w));
  *(ushort4*)(out + (size_t)n*1024 + ch0) = o;
}

// ---------------- generic fused GATv2 conv, dual-stream softmax ----------------
template<int H, int THREADS, int VPT, bool ONLY0, bool OUTBF, bool INBF>
__global__ __launch_bounds__(THREADS) void conv_kernel(
    const int* __restrict__ rowptr, const int* __restrict__ srcs, const float* __restrict__ eav,
    const float* __restrict__ loop_attr, const int* __restrict__ ntype,
    const void* __restrict__ Xv, int stride, int xr_off,
    const float* __restrict__ we, const float* __restrict__ att, const float* __restrict__ bias,
    void* __restrict__ out)
{
  const int HC = THREADS*VPT;
  const int TPH = THREADS/H;
  int n = blockIdx.x;
  if (ONLY0 && ntype[n] != 0) return;
  int tid = threadIdx.x;
  int ch0 = tid * VPT;
  const float* Xf = (const float*)Xv;
  const unsigned short* Xb = (const unsigned short*)Xv;
  float wev[VPT], atv[VPT], biv[VPT], xrv[VPT];
#pragma unroll
  for (int v=0; v<VPT; ++v){
    int ch = ch0+v;
    wev[v]=we[ch]; atv[v]=att[ch]; biv[v]=bias[ch];
  }
  if constexpr (INBF){
    ushort4 q = *(const ushort4*)(Xb + (size_t)n*stride + xr_off + ch0);
    xrv[0]=bf2f(q.x); xrv[1]=bf2f(q.y); xrv[2]=bf2f(q.z); xrv[3]=bf2f(q.w);
  } else {
#pragma unroll
    for (int v=0; v<VPT; ++v) xrv[v]=Xf[(size_t)n*stride + xr_off + ch0+v];
  }
  float m0=-INFINITY, l0=0.f, A0[VPT];
  float m1=-INFINITY, l1=0.f, A1[VPT];
#pragma unroll
  for (int v=0; v<VPT; ++v){ A0[v]=0.f; A1[v]=0.f; }
  int beg=rowptr[n], end=rowptr[n+1];
  for (int j=beg; j<=end; j+=2){
    bool two = (j+1) <= end;
    int s0 = (j < end) ? srcs[j] : n;
    float e0 = (j < end) ? eav[j] : loop_attr[n];
    int s1 = n; float e1 = 0.f;
    if (two){ s1 = (j+1 < end) ? srcs[j+1] : n; e1 = (j+1 < end) ? eav[j+1] : loop_attr[n]; }
    float x0[VPT], x1[VPT];
    if constexpr (INBF){
      ushort4 q0 = *(const ushort4*)(Xb + (size_t)s0*stride + ch0);
      x0[0]=bf2f(q0.x); x0[1]=bf2f(q0.y); x0[2]=bf2f(q0.z); x0[3]=bf2f(q0.w);
      if (two){
        ushort4 q1 = *(const ushort4*)(Xb + (size_t)s1*stride + ch0);
        x1[0]=bf2f(q1.x); x1[1]=bf2f(q1.y); x1[2]=bf2f(q1.z); x1[3]=bf2f(q1.w);
      } else { x1[0]=x1[1]=x1[2]=x1[3]=0.f; }
    } else if constexpr (VPT == 4){
      float4 q0 = *(const float4*)(Xf + (size_t)s0*stride + ch0);
      x0[0]=q0.x; x0[1]=q0.y; x0[2]=q0.z; x0[3]=q0.w;
      if (two){
        float4 q1 = *(const float4*)(Xf + (size_t)s1*stride + ch0);
        x1[0]=q1.x; x1[1]=q1.y; x1[2]=q1.z; x1[3]=q1.w;
      } else { x1[0]=x1[1]=x1[2]=x1[3]=0.f; }
    } else {
      float2 q0 = *(const float2*)(Xf + (size_t)s0*stride + ch0);
      x0[0]=q0.x; x0[1]=q0.y;
      if (two){
        float2 q1 = *(const float2*)(Xf + (size_t)s1*stride + ch0);
        x1[0]=q1.x; x1[1]=q1.y;
      } else { x1[0]=x1[1]=0.f; }
    }
    float p0=0.f, p1=0.f;
#pragma unroll
    for (int v=0; v<VPT; ++v){
      p0 += atv[v]*lrelu(x0[v]+xrv[v]+e0*wev[v]);
      p1 += atv[v]*lrelu(x1[v]+xrv[v]+e1*wev[v]);
    }
#pragma unroll
    for (int mm=1; mm<TPH; mm<<=1){
      p0 += __shfl_xor(p0, mm, 64);
      p1 += __shfl_xor(p1, mm, 64);
    }
    {
      float mn=fmaxf(m0,p0), sc=__expf(m0-mn), pe=__expf(p0-mn);
      l0=l0*sc+pe; m0=mn;
#pragma unroll
      for (int v=0; v<VPT; ++v) A0[v]=A0[v]*sc+pe*x0[v];
    }
    if (two){
      float mn=fmaxf(m1,p1), sc=__expf(m1-mn), pe=__expf(p1-mn);
      l1=l1*sc+pe; m1=mn;
#pragma unroll
      for (int v=0; v<VPT; ++v) A1[v]=A1[v]*sc+pe*x1[v];
    }
  }
  float mn = fmaxf(m0, m1);
  float sc0 = __expf(m0-mn), sc1 = __expf(m1-mn);
  float inv = 1.f/(l0*sc0 + l1*sc1);
  size_t baseo=(size_t)n*HC+ch0;
  if constexpr (OUTBF){
    unsigned short* ob = (unsigned short*)out;
    ushort4 o;
    o.x = f2bf(lrelu((A0[0]*sc0+A1[0]*sc1)*inv+biv[0]));
    o.y = f2bf(lrelu((A0[1]*sc0+A1[1]*sc1)*inv+biv[1]));
    o.z = f2bf(lrelu((A0[2]*sc0+A1[2]*sc1)*inv+biv[2]));
    o.w = f2bf(lrelu((A0[3]*sc0+A1[3]*sc1)*inv+biv[3]));
    *(ushort4*)(ob + baseo) = o;
  } else {
    float* of = (float*)out;
#pragma unroll
    for (int v=0; v<VPT; ++v) of[baseo+v]=lrelu((A0[v]*sc0+A1[v]*sc1)*inv+biv[v]);
  }
}

// ---------------- bf16 MFMA dual GEMM, LDS-staged via global_load_lds (m97 style) -----
template<bool OUTBF>
__global__ __launch_bounds__(256) void gemm_dual_lds(
    const short* __restrict__ Abf,
    const short* __restrict__ WlT, const short* __restrict__ WrT,
    const float* __restrict__ bl, const float* __restrict__ br,
    void* __restrict__ Out, int M, int K, int NcH, int cgrid, int rgrid)
{
  __shared__ short lds[12288];    // A: [0,8192) shorts (128 rows x 64), B: [8192,12288)
  int id = blockIdx.x;
  int xcd = id & 7, slot = id >> 3;
  int nb = slot % cgrid;
  int rowgroup = (slot / cgrid) * 8 + xcd;
  if (rowgroup >= rgrid) return;
  int row0 = rowgroup * 128;
  int NC2 = 2*NcH;
  int halfx = NcH >> 6;
  int isR = nb >= halfx;
  const short* WT = isR ? WrT : WlT;
  const float* bias = isR ? br : bl;
  int col0 = (nb - (isR ? halfx : 0)) * 64;
  int gcol0 = nb * 64;
  int tid = threadIdx.x;
  int lane = tid & 63, wave = tid >> 6;
  int wm = wave >> 1, wn = wave & 1;
  int quad = lane >> 4, l16 = lane & 15;

  const short* asrc[4];
#pragma unroll
  for (int i=0;i<4;++i){
    int c = wave*256 + i*64 + lane;
    int m = c >> 3, j = c & 7;
    int gr = row0 + m; gr = gr < M ? gr : M-1;   // clamp; never stored
    asrc[i] = Abf + (size_t)gr*K + ((j ^ (m & 7)) << 3);
  }
  const short* bsrc[2];
#pragma unroll
  for (int i=0;i<2;++i){
    int c = wave*128 + i*64 + lane;
    int nloc = c >> 3, j = c & 7;
    bsrc[i] = WT + (size_t)(col0 + nloc)*K + ((j ^ (nloc & 7)) << 3);
  }

  float biasv[2] = { bias[col0 + wn*32 + l16], bias[col0 + wn*32 + 16 + l16] };
  f32x4 acc[4][2];
#pragma unroll
  for (int f=0; f<4; ++f)
#pragma unroll
    for (int g=0; g<2; ++g) acc[f][g] = (f32x4){0.f,0.f,0.f,0.f};

  int niter = K >> 6;
  for (int it=0; it<niter; ++it){
    int k0 = it << 6;
#pragma unroll
    for (int i=0;i<4;++i)
      __builtin_amdgcn_global_load_lds(asrc[i] + k0, &lds[(wave*256 + i*64)*8], 16, 0, 0);
#pragma unroll
    for (int i=0;i<2;++i)
      __builtin_amdgcn_global_load_lds(bsrc[i] + k0, &lds[8192 + (wave*128 + i*64)*8], 16, 0, 0);
    __syncthreads();
#pragma unroll
    for (int s=0; s<2; ++s){
      int t = s*4 + quad;
      bf16x8 af[4], bfv[2];
#pragma unroll
      for (int f=0; f<4; ++f){
        int m = wm*64 + f*16 + l16;
        af[f] = *(const bf16x8*)&lds[m*64 + ((t ^ (m & 7)) << 3)];
      }
#pragma unroll
      for (int g=0; g<2; ++g){
        int nloc = wn*32 + g*16 + l16;
        bfv[g] = *(const bf16x8*)&lds[8192 + nloc*64 + ((t ^ (nloc & 7)) << 3)];
      }
#pragma unroll
      for (int f=0; f<4; ++f)
#pragma unroll
        for (int g=0; g<2; ++g)
          acc[f][g] = __builtin_amdgcn_mfma_f32_16x16x32_bf16(af[f], bfv[g], acc[f][g], 0,0,0);
    }
    __syncthreads();
  }

#pragma unroll
  for (int f=0; f<4; ++f){
    int rbase = row0 + wm*64 + f*16 + quad*4;
#pragma unroll
    for (int r=0; r<4; ++r){
      int rr = rbase + r;
      if (rr < M){
#pragma unroll
        for (int g=0; g<2; ++g){
          int cc = gcol0 + wn*32 + g*16 + l16;
          float val = acc[f][g][r] + biasv[g];
          if constexpr (OUTBF) ((unsigned short*)Out)[(size_t)rr*NC2 + cc] = f2bf(val);
          else                 ((float*)Out)[(size_t)rr*NC2 + cc] = val;
        }
      }
    }
  }
}

// ---------------- fused pool (sorted batch, binary search) + MLP head ----------------
__device__ __forceinline__ int lbound(const int* __restrict__ a, int n, int key){
  int lo = 0, hi = n;
  while (lo < hi){ int mid = (lo+hi) >> 1; if (a[mid] < key) lo = mid+1; else hi = mid; }
  return lo;
}

__global__ __launch_bounds__(128) void head_kernel(
    const float* __restrict__ h3, const int* __restrict__ ntype, const int* __restrict__ batch,
    const float* __restrict__ m1w, const float* __restrict__ m1b,
    const float* __restrict__ g1, const float* __restrict__ b1,
    const float* __restrict__ m2w, const float* __restrict__ m2b,
    const float* __restrict__ g2, const float* __restrict__ b2,
    const float* __restrict__ m3w, const float* __restrict__ m3b,
    float* __restrict__ out)
{
  __shared__ float p[128];
  __shared__ float hb[128];
  __shared__ float red[128];
  int b = blockIdx.x, j = threadIdx.x;
  int lo = lbound(batch, NN, b);
  int hi = lbound(batch, NN, b+1);
  float s = 0.f, cnt = 0.f;
  int n = lo;
  for (; n + 3 < hi; n += 4){
    float w0 = (ntype[n]   == 0) ? 1.f : 0.f;
    float w1 = (ntype[n+1] == 0) ? 1.f : 0.f;
    float w2 = (ntype[n+2] == 0) ? 1.f : 0.f;
    float w3 = (ntype[n+3] == 0) ? 1.f : 0.f;
    s += w0*h3[(size_t)n*128 + j]     + w1*h3[(size_t)(n+1)*128 + j]
       + w2*h3[(size_t)(n+2)*128 + j] + w3*h3[(size_t)(n+3)*128 + j];
    cnt += w0 + w1 + w2 + w3;
  }
  for (; n < hi; ++n){
    float w = (ntype[n] == 0) ? 1.f : 0.f;
    s += w*h3[(size_t)n*128 + j];
    cnt += w;
  }
  p[j] = s / fmaxf(cnt, 1.f);
  __syncthreads();
  float a = m1b[j];
  for (int k=0; k<128; ++k) a += p[k]*m1w[k*128 + j];
  red[j] = a; __syncthreads();
  for (int off=64; off>0; off>>=1){ if (j<off) red[j] += red[j+off]; __syncthreads(); }
  float mu = red[0] * (1.f/128.f);
  __syncthreads();
  float d = a - mu;
  red[j] = d*d; __syncthreads();
  for (int off=64; off>0; off>>=1){ if (j<off) red[j] += red[j+off]; __syncthreads(); }
  float var = red[0] * (1.f/128.f);
  __syncthreads();
  hb[j] = lrelu(d * rsqrtf(var + 1e-5f) * g1[j] + b1[j]);
  __syncthreads();
  float a2 = 0.f;
  if (j < 64){
    a2 = m2b[j];
    for (int k=0; k<128; ++k) a2 += hb[k]*m2w[k*64 + j];
  }
  red[j] = (j<64) ? a2 : 0.f; __syncthreads();
  for (int off=64; off>0; off>>=1){ if (j<off) red[j] += red[j+off]; __syncthreads(); }
  float mu2 = red[0] * (1.f/64.f);
  __syncthreads();
  float d2 = a2 - mu2;
  red[j] = (j<64) ? d2*d2 : 0.f; __syncthreads();
  for (int off=64; off>0; off>>=1){ if (j<off) red[j] += red[j+off]; __syncthreads(); }
  float var2 = red[0] * (1.f/64.f);
  __syncthreads();
  if (j < 64) hb[j] = lrelu(d2 * rsqrtf(var2 + 1e-5f) * g2[j] + b2[j]);
  __syncthreads();
  if (j == 0){
    float o = m3b[0];
    for (int k=0; k<64; ++k) o += hb[k]*m3w[k];
    out[b] = o;
  }
}

extern "C" void kernel_launch(void* const* d_in, const int* in_sizes, int n_in,
                              void* d_out, int out_size, void* d_ws, size_t ws_size,
                              hipStream_t stream)
{
  const float* x        = (const float*)d_in[0];
  const int*   ntype    = (const int*)d_in[1];
  const int*   ei       = (const int*)d_in[2];
  const float* eattr    = (const float*)d_in[3];
  const int*   batch    = (const int*)d_in[4];
  const float* vp_w     = (const float*)d_in[5];
  const float* vp_b     = (const float*)d_in[6];
  const float* type_emb = (const float*)d_in[7];
  const float* c1_wl = (const float*)d_in[8];  const float* c1_bl = (const float*)d_in[9];
  const float* c1_wr = (const float*)d_in[10]; const float* c1_br = (const float*)d_in[11];
  const float* c1_we = (const float*)d_in[12]; const float* c1_att= (const float*)d_in[13];
  const float* c1_bias=(const float*)d_in[14];
  const float* c2_wl = (const float*)d_in[15]; const float* c2_bl = (const float*)d_in[16];
  const float* c2_wr = (const float*)d_in[17]; const float* c2_br = (const float*)d_in[18];
  const float* c2_we = (const float*)d_in[19]; const float* c2_att= (const float*)d_in[20];
  const float* c2_bias=(const float*)d_in[21];
  const float* c3_wl = (const float*)d_in[22]; const float* c3_bl = (const float*)d_in[23];
  const float* c3_wr = (const float*)d_in[24]; const float* c3_br = (const float*)d_in[25];
  const float* c3_we = (const float*)d_in[26]; const float* c3_att= (const float*)d_in[27];
  const float* c3_bias=(const float*)d_in[28];
  const float* m1_w = (const float*)d_in[29]; const float* m1_b = (const float*)d_in[30];
  const float* ln1_g= (const float*)d_in[31]; const float* ln1_b= (const float*)d_in[32];
  const float* m2_w = (const float*)d_in[33]; const float* m2_b = (const float*)d_in[34];
  const float* ln2_g= (const float*)d_in[35]; const float* ln2_b= (const float*)d_in[36];
  const float* m3_w = (const float*)d_in[37]; const float* m3_b = (const float*)d_in[38];
  const int* esrc = ei;
  const int* edst = ei + NE;
  float* outp = (float*)d_out;
  (void)in_sizes; (void)n_in; (void)out_size; (void)ws_size;

  // ---- workspace arena ----
  char* w = (char*)d_ws;
  auto alloc = [&](size_t bytes) -> void* {
    void* p = (void*)w;
    w += (bytes + 255) & ~(size_t)255;
    return p;
  };
  unsigned short* h1bf = (unsigned short*)alloc((size_t)NN*1024*2);  // conv1 out, bf16
  unsigned short* X2   = (unsigned short*)alloc((size_t)NN*512*2);   // [xl2 | xr2] bf16
  unsigned short* h2bf = (unsigned short*)alloc((size_t)NN*256*2);   // conv2 out, bf16
  float* X3   = (float*)alloc((size_t)NN*256*4);    // [xl3 | xr3] fp32
  float* h3   = (float*)alloc((size_t)NN*128*4);    // conv3 out (type0 rows only)
  unsigned short* W2lT = (unsigned short*)alloc((size_t)256*1024*2);
  unsigned short* W2rT = (unsigned short*)alloc((size_t)256*1024*2);
  unsigned short* W3lT = (unsigned short*)alloc((size_t)128*256*2);
  unsigned short* W3rT = (unsigned short*)alloc((size_t)128*256*2);
  float* Ul   = (float*)alloc(1024*4);
  float* CTl  = (float*)alloc(2048*4);
  float* Ur   = (float*)alloc(1024*4);
  float* CT2  = (float*)alloc(4096*4);
  float* scores = (float*)alloc((size_t)E2*8*4);
  const int zero_words = 3*NN;                       // deg, rowctr, loop_sum
  float* zbase = (float*)alloc((size_t)zero_words*4);
  int*   deg      = (int*)zbase;
  int*   rowctr   = (int*)(zbase + NN);
  float* loop_sum = zbase + 2*NN;
  float* loop_attr= (float*)alloc((size_t)NN*4);
  int*   rowptr   = (int*)alloc((size_t)(NN+1)*4);
  int*   srcs     = (int*)alloc((size_t)NE*4);
  int*   dsts     = (int*)alloc((size_t)NE*4);
  float* eav      = (float*)alloc((size_t)NE*4);

  // ---- pipeline (11 dispatches) ----
  prep_kernel<<<180, 256, 0, stream>>>(vp_w, vp_b, type_emb,
      c1_wl, c1_bl, c1_wr, c1_br, Ul, CTl, Ur, CT2,
      c2_wl, c2_wr, c3_wl, c3_wr, W2lT, W2rT, W3lT, W3rT,
      zbase, zero_words);
  count_kernel<<<(NE+255)/256, 256, 0, stream>>>(edst, eattr, deg, loop_sum);
  scan_kernel<<<1, 1024, 0, stream>>>(deg, loop_sum, rowptr, loop_attr);
  fill_kernel<<<(NE+255)/256, 256, 0, stream>>>(esrc, edst, eattr, rowptr, rowctr,
                                                srcs, dsts, eav);
  conv1_score<<<2048, 256, 0, stream>>>(srcs, dsts, eav, loop_attr, x, ntype,
      Ul, Ur, CT2, c1_we, c1_att, scores);
  conv1_agg<<<NN, 256, 0, stream>>>(rowptr, srcs, scores, x, ntype,
      Ul, CTl, c1_bias, h1bf);
  // c2: X2[10000,512] bf16, K=1024, NcH=256: cgrid=8, rgrid=79 -> 640 blocks
  gemm_dual_lds<true><<<640, 256, 0, stream>>>(
      (const short*)h1bf, (const short*)W2lT, (const short*)W2rT, c2_bl, c2_br,
      (void*)X2, NN, 1024, 256, 8, 79);
  conv_kernel<2,64,4,false,true,true><<<NN, 64, 0, stream>>>(rowptr, srcs, eav, loop_attr, ntype,
      (const void*)X2, 512, 256, c2_we, c2_att, c2_bias, h2bf);
  // c3: X3[10000,256] fp32, K=256, NcH=128: cgrid=4, rgrid=79 -> 320 blocks
  gemm_dual_lds<false><<<320, 256, 0, stream>>>(
      (const short*)h2bf, (const short*)W3lT, (const short*)W3rT, c3_bl, c3_br,
      (void*)X3, NN, 256, 128, 4, 79);
  conv_kernel<1,64,2,true,false,false><<<NN, 64, 0, stream>>>(rowptr, srcs, eav, loop_attr, ntype,
      (const void*)X3, 256, 128, c3_we, c3_att, c3_bias, h3);
  head_kernel<<<NBATCH, 128, 0, stream>>>(h3, ntype, batch, m1_w, m1_b, ln1_g, ln1_b,
                                          m2_w, m2_b, ln2_g, ln2_b, m3_w, m3_b, outp);
}

// Round 11
// 320.457 us; speedup vs baseline: 1.2916x; 1.0193x over previous
//
#include <hip/hip_runtime.h>
#include <math.h>

#define NN 10000
#define NE 100000
#define E2 (NE + NN)
#define NBATCH 64

typedef short bf16x8 __attribute__((ext_vector_type(8)));
typedef float f32x4 __attribute__((ext_vector_type(4)));

__device__ __forceinline__ float lrelu(float v){ return v > 0.f ? v : 0.2f*v; }

// fp32 -> bf16 round-to-nearest-even
__device__ __forceinline__ unsigned short f2bf(float x){
  unsigned int u = __float_as_uint(x);
  u += 0x7fffu + ((u >> 16) & 1u);
  return (unsigned short)(u >> 16);
}
__device__ __forceinline__ float bf2f(unsigned short u){
  return __uint_as_float(((unsigned int)u) << 16);
}

// ---------------- prep: zero + c1 precompute (+CT2) + 4 weight transposes --------------
__global__ __launch_bounds__(256) void prep_kernel(
    const float* __restrict__ vp_w, const float* __restrict__ vp_b,
    const float* __restrict__ type_emb,
    const float* __restrict__ c1_wl, const float* __restrict__ c1_bl,
    const float* __restrict__ c1_wr, const float* __restrict__ c1_br,
    float* __restrict__ Ul, float* __restrict__ CTl,
    float* __restrict__ Ur, float* __restrict__ CT2,
    const float* __restrict__ c2_wl, const float* __restrict__ c2_wr,
    const float* __restrict__ c3_wl, const float* __restrict__ c3_wr,
    unsigned short* __restrict__ W2lT, unsigned short* __restrict__ W2rT,
    unsigned short* __restrict__ W3lT, unsigned short* __restrict__ W3rT,
    float* __restrict__ zbase, int zero_words)
{
  __shared__ float t[64][65];
  int b = blockIdx.x;
  int tid = threadIdx.x;
  if (b < 144){
    const float* in; unsigned short* out; int K, N, idx;
    if (b < 64)      { in=c2_wl; out=W2lT; K=1024; N=256; idx=b; }
    else if (b <128) { in=c2_wr; out=W2rT; K=1024; N=256; idx=b-64; }
    else if (b <136) { in=c3_wl; out=W3lT; K=256;  N=128; idx=b-128; }
    else             { in=c3_wr; out=W3rT; K=256;  N=128; idx=b-136; }
    int K64 = K >> 6;
    int kx = idx % K64, nx = idx / K64;
    int k0 = kx*64, n0 = nx*64;
    int lr = tid >> 4;
    int lc = (tid & 15) * 4;
#pragma unroll
    for (int i=0;i<4;++i){
      int r = lr + i*16;
      float4 v = *(const float4*)(in + (size_t)(k0+r)*N + n0 + lc);
      t[r][lc+0]=v.x; t[r][lc+1]=v.y; t[r][lc+2]=v.z; t[r][lc+3]=v.w;
    }
    __syncthreads();
    int sr = tid >> 3;
    int sc = (tid & 7) * 8;
#pragma unroll
    for (int i=0;i<2;++i){
      int n = sr + i*32;
      unsigned short tmp[8];
#pragma unroll
      for (int j=0;j<8;++j) tmp[j] = f2bf(t[sc+j][n]);
      unsigned short* op = out + (size_t)(n0+n)*K + k0 + sc;
      *(ushort4*)op       = make_ushort4(tmp[0],tmp[1],tmp[2],tmp[3]);
      *(ushort4*)(op + 4) = make_ushort4(tmp[4],tmp[5],tmp[6],tmp[7]);
    }
  } else if (b < 148){
    int j = (b-144)*256 + tid;
    float ul=0.f, c0l=0.f, c1l=0.f, ur=0.f, c0r=0.f, c1r=0.f;
    for (int k=0; k<128; ++k){
      float a = c1_wl[k*1024 + j], bb = c1_wr[k*1024 + j];
      float vw = vp_w[k], vb = vp_b[k], t0 = type_emb[k], t1 = type_emb[128+k];
      ul += vw*a; ur += vw*bb;
      c0l += (vb+t0)*a; c1l += (vb+t1)*a;
      c0r += (vb+t0)*bb; c1r += (vb+t1)*bb;
    }
    float bl = c1_bl[j], br = c1_br[j];
    Ul[j]=ul; Ur[j]=ur;
    CTl[j]      = c0l + bl;
    CTl[1024+j] = c1l + bl;
    // CT2[ts*2+tn] = CTl[ts] + CTr[tn] (both with their biases)
    CT2[j]        = (c0l+bl) + (c0r+br);
    CT2[1024+j]   = (c0l+bl) + (c1r+br);
    CT2[2048+j]   = (c1l+bl) + (c0r+br);
    CT2[3072+j]   = (c1l+bl) + (c1r+br);
  } else {
    for (int i = (b-148)*256 + tid; i < zero_words; i += 32*256)
      zbase[i] = 0.f;
  }
}

// ---------------- CSR build: 3 kernels (count -> scan -> fill) ----------------
__global__ void count_kernel(const int* __restrict__ dst, const float* __restrict__ ea,
                             int* __restrict__ deg, float* __restrict__ loop_sum){
  int e = blockIdx.x*256 + threadIdx.x;
  if (e < NE){
    int d = dst[e];
    atomicAdd(&deg[d], 1);
    atomicAdd(&loop_sum[d], ea[e]);
  }
}

__global__ __launch_bounds__(1024) void scan_kernel(const int* __restrict__ deg,
    const float* __restrict__ loop_sum, int* __restrict__ rowptr, float* __restrict__ loop_attr){
  __shared__ int wsum[16];
  __shared__ int carry_s;
  int tid = threadIdx.x;
  int lane = tid & 63, wid = tid >> 6;
  if (tid == 0) carry_s = 0;
  __syncthreads();
  for (int base = 0; base < NN; base += 1024){
    int i = base + tid;
    int v = (i < NN) ? deg[i] : 0;
    int incl = v;
#pragma unroll
    for (int off = 1; off < 64; off <<= 1){
      int t = __shfl_up(incl, off, 64);
      if (lane >= off) incl += t;
    }
    if (lane == 63) wsum[wid] = incl;
    __syncthreads();
    int pre = carry_s;
    for (int w = 0; w < wid; ++w) pre += wsum[w];
    if (i < NN){
      rowptr[i] = pre + incl - v;                           // exclusive scan
      loop_attr[i] = loop_sum[i] / fmaxf((float)v, 1.f);    // fill='mean'
    }
    __syncthreads();
    if (tid == 0){
      int t = 0;
      for (int w = 0; w < 16; ++w) t += wsum[w];
      carry_s += t;
    }
    __syncthreads();
  }
  if (tid == 0) rowptr[NN] = carry_s;
}

__global__ void fill_kernel(const int* __restrict__ src, const int* __restrict__ dst,
                            const float* __restrict__ ea, const int* __restrict__ rowptr,
                            int* __restrict__ rowctr, int* __restrict__ srcs,
                            int* __restrict__ dsts, float* __restrict__ eav){
  int e = blockIdx.x*256 + threadIdx.x;
  if (e < NE){
    int d = dst[e];
    int p = rowptr[d] + atomicAdd(&rowctr[d], 1);
    srcs[p] = src[e];
    dsts[p] = d;
    eav[p] = ea[e];
  }
}

// ---------------- conv1 pass 1: per-edge head scores (edge-parallel, no chain) --------
__global__ __launch_bounds__(256) void conv1_score(
    const int* __restrict__ srcs, const int* __restrict__ dsts, const float* __restrict__ eav,
    const float* __restrict__ loop_attr, const float* __restrict__ x, const int* __restrict__ ntype,
    const float* __restrict__ Ul, const float* __restrict__ Ur, const float* __restrict__ CT2,
    const float* __restrict__ we, const float* __restrict__ att,
    float* __restrict__ scores)
{
  __shared__ float ldsct[4096];
  int tid = threadIdx.x;
  for (int i = tid; i < 1024; i += 256)
    *(float4*)&ldsct[i*4] = *(const float4*)&CT2[i*4];
  int te = tid & 127;
  int sub = tid >> 7;
  int ch0 = te * 8;
  float ul[8], ur[8], wev[8], atv[8];
#pragma unroll
  for (int v=0; v<8; ++v){
    ul[v]=Ul[ch0+v]; ur[v]=Ur[ch0+v]; wev[v]=we[ch0+v]; atv[v]=att[ch0+v];
  }
  __syncthreads();
  for (int j = blockIdx.x*2 + sub; j < E2; j += gridDim.x*2){
    int s, d; float ea;
    if (j < NE){ s = srcs[j]; d = dsts[j]; ea = eav[j]; }
    else       { s = j - NE;  d = s;       ea = loop_attr[s]; }
    float xs = x[s], xn = x[d];
    int tt = ntype[s]*2 + ntype[d];
    const float* cp = &ldsct[tt*1024 + ch0];
    float4 c0 = *(const float4*)cp;
    float4 c1 = *(const float4*)(cp+4);
    float ct[8] = {c0.x,c0.y,c0.z,c0.w,c1.x,c1.y,c1.z,c1.w};
    float p = 0.f;
#pragma unroll
    for (int v=0; v<8; ++v){
      float z = fmaf(xs, ul[v], fmaf(xn, ur[v], fmaf(ea, wev[v], ct[v])));
      p += atv[v]*lrelu(z);
    }
#pragma unroll
    for (int mm=1; mm<16; mm<<=1) p += __shfl_xor(p, mm, 16);
    if ((te & 15) == 0) scores[(size_t)j*8 + (te>>4)] = p;
  }
}

// ---------------- conv1 pass 2: softmax + rank-3 aggregation + epilogue ----------------
__global__ __launch_bounds__(256) void conv1_agg(
    const int* __restrict__ rowptr, const int* __restrict__ srcs,
    const float* __restrict__ scores, const float* __restrict__ x, const int* __restrict__ ntype,
    const float* __restrict__ Ul, const float* __restrict__ CTl,
    const float* __restrict__ bias, unsigned short* __restrict__ out)
{
  int n = blockIdx.x;
  int tid = threadIdx.x;
  int h = tid >> 5, el = tid & 31;
  int beg = rowptr[n], deg = rowptr[n+1] - beg;
  int cnt = deg + 1;
  float m = -1e30f, l = 0.f, s1 = 0.f, s20 = 0.f;
  for (int i = el; i < cnt; i += 32){
    int pos; int s;
    if (i < deg){ pos = beg + i; s = srcs[pos]; }
    else        { pos = NE + n;  s = n; }
    float p = scores[(size_t)pos*8 + h];
    float xs = x[s];
    float w0 = (ntype[s] == 0) ? 1.f : 0.f;
    float mn = fmaxf(m, p), f = __expf(m-mn), pe = __expf(p-mn);
    l = l*f + pe; s1 = s1*f + pe*xs; s20 = s20*f + pe*w0; m = mn;
  }
#pragma unroll
  for (int off=1; off<32; off<<=1){
    float mb = __shfl_xor(m, off, 32), lb = __shfl_xor(l, off, 32);
    float s1b = __shfl_xor(s1, off, 32), s20b = __shfl_xor(s20, off, 32);
    float mn = fmaxf(m, mb), fa = __expf(m-mn), fb = __expf(mb-mn);
    l = l*fa + lb*fb; s1 = s1*fa + s1b*fb; s20 = s20*fa + s20b*fb; m = mn;
  }
  float inv = 1.f/l;
  s1 *= inv; s20 *= inv;
  float s21 = 1.f - s20;
  int ch0 = tid * 4;       // head of ch0..ch0+3 == tid>>5 == h
  float4 u  = *(const float4*)(Ul + ch0);
  float4 t0 = *(const float4*)(CTl + ch0);
  float4 t1 = *(const float4*)(CTl + 1024 + ch0);
  float4 bi = *(const float4*)(bias + ch0);
  ushort4 o;
  o.x = f2bf(lrelu(s1*u.x + s20*t0.x + s21*t1.x + bi.x));
  o.y = f2bf(lrelu(s1*u.y + s20*t0.y + s21*t1.y + bi.y));
  o.z = f2bf(lrelu(s1*u.z + s20*t0.z + s21*t1.z + bi.z));
  o.w = f2bf(lrelu(s1*u.w + s20*t0.w + s21*t1.w + bi.w));
  *(ushort4*)(out + (size_t)n*1024 + ch0) = o;
}

// ---------------- generic fused GATv2 conv, QUAD-stream online softmax ----------------
// 4 independent (m,l,A) states -> 4 gathers in flight; serial chain deg/4.
// Stream 0 always non-empty (cnt>=1), so sequential merges into it are NaN-safe
// (empty streams have m=-inf -> exp(-inf)=0 contribution).
template<int H, int THREADS, int VPT, bool ONLY0, bool OUTBF, bool INBF>
__global__ __launch_bounds__(THREADS) void conv_kernel(
    const int* __restrict__ rowptr, const int* __restrict__ srcs, const float* __restrict__ eav,
    const float* __restrict__ loop_attr, const int* __restrict__ ntype,
    const void* __restrict__ Xv, int stride, int xr_off,
    const float* __restrict__ we, const float* __restrict__ att, const float* __restrict__ bias,
    void* __restrict__ out)
{
  const int HC = THREADS*VPT;
  const int TPH = THREADS/H;
  int n = blockIdx.x;
  if (ONLY0 && ntype[n] != 0) return;
  int tid = threadIdx.x;
  int ch0 = tid * VPT;
  const float* Xf = (const float*)Xv;
  const unsigned short* Xb = (const unsigned short*)Xv;
  float wev[VPT], atv[VPT], biv[VPT], xrv[VPT];
#pragma unroll
  for (int v=0; v<VPT; ++v){
    int ch = ch0+v;
    wev[v]=we[ch]; atv[v]=att[ch]; biv[v]=bias[ch];
  }
  if constexpr (INBF){
    ushort4 q = *(const ushort4*)(Xb + (size_t)n*stride + xr_off + ch0);
    xrv[0]=bf2f(q.x); xrv[1]=bf2f(q.y); xrv[2]=bf2f(q.z); xrv[3]=bf2f(q.w);
  } else {
#pragma unroll
    for (int v=0; v<VPT; ++v) xrv[v]=Xf[(size_t)n*stride + xr_off + ch0+v];
  }
  float ms[4], ls[4], A[4][VPT];
#pragma unroll
  for (int k=0; k<4; ++k){
    ms[k] = -INFINITY; ls[k] = 0.f;
#pragma unroll
    for (int v=0; v<VPT; ++v) A[k][v] = 0.f;
  }
  int beg=rowptr[n], end=rowptr[n+1];   // index end = self-loop
  float la = loop_attr[n];
  for (int j=beg; j<=end; j+=4){
    bool val[4]; int sx[4]; float ex[4];
#pragma unroll
    for (int k=0; k<4; ++k){
      int pos = j + k;
      val[k] = pos <= end;
      sx[k] = (!val[k] || pos == end) ? n : srcs[pos];
      ex[k] = !val[k] ? 0.f : (pos == end ? la : eav[pos]);
    }
    float xv[4][VPT];
#pragma unroll
    for (int k=0; k<4; ++k){
      if constexpr (INBF){
        ushort4 q = *(const ushort4*)(Xb + (size_t)sx[k]*stride + ch0);
        xv[k][0]=bf2f(q.x); xv[k][1]=bf2f(q.y); xv[k][2]=bf2f(q.z); xv[k][3]=bf2f(q.w);
      } else if constexpr (VPT == 4){
        float4 q = *(const float4*)(Xf + (size_t)sx[k]*stride + ch0);
        xv[k][0]=q.x; xv[k][1]=q.y; xv[k][2]=q.z; xv[k][3]=q.w;
      } else {
        float2 q = *(const float2*)(Xf + (size_t)sx[k]*stride + ch0);
        xv[k][0]=q.x; xv[k][1]=q.y;
      }
    }
    float p[4];
#pragma unroll
    for (int k=0; k<4; ++k){
      float acc = 0.f;
#pragma unroll
      for (int v=0; v<VPT; ++v)
        acc += atv[v]*lrelu(xv[k][v]+xrv[v]+ex[k]*wev[v]);
      p[k] = acc;
    }
#pragma unroll
    for (int mm=1; mm<TPH; mm<<=1){
#pragma unroll
      for (int k=0; k<4; ++k) p[k] += __shfl_xor(p[k], mm, 64);
    }
#pragma unroll
    for (int k=0; k<4; ++k){
      if (val[k]){
        float mn=fmaxf(ms[k],p[k]), sc=__expf(ms[k]-mn), pe=__expf(p[k]-mn);
        ls[k]=ls[k]*sc+pe; ms[k]=mn;
#pragma unroll
        for (int v=0; v<VPT; ++v) A[k][v]=A[k][v]*sc+pe*xv[k][v];
      }
    }
  }
  // sequential merge into stream 0 (always non-empty)
#pragma unroll
  for (int k=1; k<4; ++k){
    float mn = fmaxf(ms[0], ms[k]);
    float fa = __expf(ms[0]-mn), fb = __expf(ms[k]-mn);
    ls[0] = ls[0]*fa + ls[k]*fb;
#pragma unroll
    for (int v=0; v<VPT; ++v) A[0][v] = A[0][v]*fa + A[k][v]*fb;
    ms[0] = mn;
  }
  float inv = 1.f/ls[0];
  size_t baseo=(size_t)n*HC+ch0;
  if constexpr (OUTBF){
    unsigned short* ob = (unsigned short*)out;
    ushort4 o;
    o.x = f2bf(lrelu(A[0][0]*inv+biv[0]));
    o.y = f2bf(lrelu(A[0][1]*inv+biv[1]));
    o.z = f2bf(lrelu(A[0][2]*inv+biv[2]));
    o.w = f2bf(lrelu(A[0][3]*inv+biv[3]));
    *(ushort4*)(ob + baseo) = o;
  } else {
    float* of = (float*)out;
#pragma unroll
    for (int v=0; v<VPT; ++v) of[baseo+v]=lrelu(A[0][v]*inv+biv[v]);
  }
}

// ---------------- bf16 MFMA dual GEMM, LDS-staged via global_load_lds (m97 style) -----
template<bool OUTBF>
__global__ __launch_bounds__(256) void gemm_dual_lds(
    const short* __restrict__ Abf,
    const short* __restrict__ WlT, const short* __restrict__ WrT,
    const float* __restrict__ bl, const float* __restrict__ br,
    void* __restrict__ Out, int M, int K, int NcH, int cgrid, int rgrid)
{
  __shared__ short lds[12288];    // A: [0,8192) shorts (128 rows x 64), B: [8192,12288)
  int id = blockIdx.x;
  int xcd = id & 7, slot = id >> 3;
  int nb = slot % cgrid;
  int rowgroup = (slot / cgrid) * 8 + xcd;
  if (rowgroup >= rgrid) return;
  int row0 = rowgroup * 128;
  int NC2 = 2*NcH;
  int halfx = NcH >> 6;
  int isR = nb >= halfx;
  const short* WT = isR ? WrT : WlT;
  const float* bias = isR ? br : bl;
  int col0 = (nb - (isR ? halfx : 0)) * 64;
  int gcol0 = nb * 64;
  int tid = threadIdx.x;
  int lane = tid & 63, wave = tid >> 6;
  int wm = wave >> 1, wn = wave & 1;
  int quad = lane >> 4, l16 = lane & 15;

  const short* asrc[4];
#pragma unroll
  for (int i=0;i<4;++i){
    int c = wave*256 + i*64 + lane;
    int m = c >> 3, j = c & 7;
    int gr = row0 + m; gr = gr < M ? gr : M-1;   // clamp; never stored
    asrc[i] = Abf + (size_t)gr*K + ((j ^ (m & 7)) << 3);
  }
  const short* bsrc[2];
#pragma unroll
  for (int i=0;i<2;++i){
    int c = wave*128 + i*64 + lane;
    int nloc = c >> 3, j = c & 7;
    bsrc[i] = WT + (size_t)(col0 + nloc)*K + ((j ^ (nloc & 7)) << 3);
  }

  float biasv[2] = { bias[col0 + wn*32 + l16], bias[col0 + wn*32 + 16 + l16] };
  f32x4 acc[4][2];
#pragma unroll
  for (int f=0; f<4; ++f)
#pragma unroll
    for (int g=0; g<2; ++g) acc[f][g] = (f32x4){0.f,0.f,0.f,0.f};

  int niter = K >> 6;
  for (int it=0; it<niter; ++it){
    int k0 = it << 6;
#pragma unroll
    for (int i=0;i<4;++i)
      __builtin_amdgcn_global_load_lds(asrc[i] + k0, &lds[(wave*256 + i*64)*8], 16, 0, 0);
#pragma unroll
    for (int i=0;i<2;++i)
      __builtin_amdgcn_global_load_lds(bsrc[i] + k0, &lds[8192 + (wave*128 + i*64)*8], 16, 0, 0);
    __syncthreads();
#pragma unroll
    for (int s=0; s<2; ++s){
      int t = s*4 + quad;
      bf16x8 af[4], bfv[2];
#pragma unroll
      for (int f=0; f<4; ++f){
        int m = wm*64 + f*16 + l16;
        af[f] = *(const bf16x8*)&lds[m*64 + ((t ^ (m & 7)) << 3)];
      }
#pragma unroll
      for (int g=0; g<2; ++g){
        int nloc = wn*32 + g*16 + l16;
        bfv[g] = *(const bf16x8*)&lds[8192 + nloc*64 + ((t ^ (nloc & 7)) << 3)];
      }
#pragma unroll
      for (int f=0; f<4; ++f)
#pragma unroll
        for (int g=0; g<2; ++g)
          acc[f][g] = __builtin_amdgcn_mfma_f32_16x16x32_bf16(af[f], bfv[g], acc[f][g], 0,0,0);
    }
    __syncthreads();
  }

#pragma unroll
  for (int f=0; f<4; ++f){
    int rbase = row0 + wm*64 + f*16 + quad*4;
#pragma unroll
    for (int r=0; r<4; ++r){
      int rr = rbase + r;
      if (rr < M){
#pragma unroll
        for (int g=0; g<2; ++g){
          int cc = gcol0 + wn*32 + g*16 + l16;
          float val = acc[f][g][r] + biasv[g];
          if constexpr (OUTBF) ((unsigned short*)Out)[(size_t)rr*NC2 + cc] = f2bf(val);
          else                 ((float*)Out)[(size_t)rr*NC2 + cc] = val;
        }
      }
    }
  }
}

// ---------------- fused pool (sorted batch, binary search) + MLP head ----------------
__device__ __forceinline__ int lbound(const int* __restrict__ a, int n, int key){
  int lo = 0, hi = n;
  while (lo < hi){ int mid = (lo+hi) >> 1; if (a[mid] < key) lo = mid+1; else hi = mid; }
  return lo;
}

__global__ __launch_bounds__(128) void head_kernel(
    const float* __restrict__ h3, const int* __restrict__ ntype, const int* __restrict__ batch,
    const float* __restrict__ m1w, const float* __restrict__ m1b,
    const float* __restrict__ g1, const float* __restrict__ b1,
    const float* __restrict__ m2w, const float* __restrict__ m2b,
    const float* __restrict__ g2, const float* __restrict__ b2,
    const float* __restrict__ m3w, const float* __restrict__ m3b,
    float* __restrict__ out)
{
  __shared__ float p[128];
  __shared__ float hb[128];
  __shared__ float red[128];
  int b = blockIdx.x, j = threadIdx.x;
  int lo = lbound(batch, NN, b);
  int hi = lbound(batch, NN, b+1);
  float s = 0.f, cnt = 0.f;
  int n = lo;
  for (; n + 3 < hi; n += 4){
    float w0 = (ntype[n]   == 0) ? 1.f : 0.f;
    float w1 = (ntype[n+1] == 0) ? 1.f : 0.f;
    float w2 = (ntype[n+2] == 0) ? 1.f : 0.f;
    float w3 = (ntype[n+3] == 0) ? 1.f : 0.f;
    s += w0*h3[(size_t)n*128 + j]     + w1*h3[(size_t)(n+1)*128 + j]
       + w2*h3[(size_t)(n+2)*128 + j] + w3*h3[(size_t)(n+3)*128 + j];
    cnt += w0 + w1 + w2 + w3;
  }
  for (; n < hi; ++n){
    float w = (ntype[n] == 0) ? 1.f : 0.f;
    s += w*h3[(size_t)n*128 + j];
    cnt += w;
  }
  p[j] = s / fmaxf(cnt, 1.f);
  __syncthreads();
  float a = m1b[j];
  for (int k=0; k<128; ++k) a += p[k]*m1w[k*128 + j];
  red[j] = a; __syncthreads();
  for (int off=64; off>0; off>>=1){ if (j<off) red[j] += red[j+off]; __syncthreads(); }
  float mu = red[0] * (1.f/128.f);
  __syncthreads();
  float d = a - mu;
  red[j] = d*d; __syncthreads();
  for (int off=64; off>0; off>>=1){ if (j<off) red[j] += red[j+off]; __syncthreads(); }
  float var = red[0] * (1.f/128.f);
  __syncthreads();
  hb[j] = lrelu(d * rsqrtf(var + 1e-5f) * g1[j] + b1[j]);
  __syncthreads();
  float a2 = 0.f;
  if (j < 64){
    a2 = m2b[j];
    for (int k=0; k<128; ++k) a2 += hb[k]*m2w[k*64 + j];
  }
  red[j] = (j<64) ? a2 : 0.f; __syncthreads();
  for (int off=64; off>0; off>>=1){ if (j<off) red[j] += red[j+off]; __syncthreads(); }
  float mu2 = red[0] * (1.f/64.f);
  __syncthreads();
  float d2 = a2 - mu2;
  red[j] = (j<64) ? d2*d2 : 0.f; __syncthreads();
  for (int off=64; off>0; off>>=1){ if (j<off) red[j] += red[j+off]; __syncthreads(); }
  float var2 = red[0] * (1.f/64.f);
  __syncthreads();
  if (j < 64) hb[j] = lrelu(d2 * rsqrtf(var2 + 1e-5f) * g2[j] + b2[j]);
  __syncthreads();
  if (j == 0){
    float o = m3b[0];
    for (int k=0; k<64; ++k) o += hb[k]*m3w[k];
    out[b] = o;
  }
}

extern "C" void kernel_launch(void* const* d_in, const int* in_sizes, int n_in,
                              void* d_out, int out_size, void* d_ws, size_t ws_size,
                              hipStream_t stream)
{
  const float* x        = (const float*)d_in[0];
  const int*   ntype    = (const int*)d_in[1];
  const int*   ei       = (const int*)d_in[2];
  const float* eattr    = (const float*)d_in[3];
  const int*   batch    = (const int*)d_in[4];
  const float* vp_w     = (const float*)d_in[5];
  const float* vp_b     = (const float*)d_in[6];
  const float* type_emb = (const float*)d_in[7];
  const float* c1_wl = (const float*)d_in[8];  const float* c1_bl = (const float*)d_in[9];
  const float* c1_wr = (const float*)d_in[10]; const float* c1_br = (const float*)d_in[11];
  const float* c1_we = (const float*)d_in[12]; const float* c1_att= (const float*)d_in[13];
  const float* c1_bias=(const float*)d_in[14];
  const float* c2_wl = (const float*)d_in[15]; const float* c2_bl = (const float*)d_in[16];
  const float* c2_wr = (const float*)d_in[17]; const float* c2_br = (const float*)d_in[18];
  const float* c2_we = (const float*)d_in[19]; const float* c2_att= (const float*)d_in[20];
  const float* c2_bias=(const float*)d_in[21];
  const float* c3_wl = (const float*)d_in[22]; const float* c3_bl = (const float*)d_in[23];
  const float* c3_wr = (const float*)d_in[24]; const float* c3_br = (const float*)d_in[25];
  const float* c3_we = (const float*)d_in[26]; const float* c3_att= (const float*)d_in[27];
  const float* c3_bias=(const float*)d_in[28];
  const float* m1_w = (const float*)d_in[29]; const float* m1_b = (const float*)d_in[30];
  const float* ln1_g= (const float*)d_in[31]; const float* ln1_b= (const float*)d_in[32];
  const float* m2_w = (const float*)d_in[33]; const float* m2_b = (const float*)d_in[34];
  const float* ln2_g= (const float*)d_in[35]; const float* ln2_b= (const float*)d_in[36];
  const float* m3_w = (const float*)d_in[37]; const float* m3_b = (const float*)d_in[38];
  const int* esrc = ei;
  const int* edst = ei + NE;
  float* outp = (float*)d_out;
  (void)in_sizes; (void)n_in; (void)out_size; (void)ws_size;

  // ---- workspace arena ----
  char* w = (char*)d_ws;
  auto alloc = [&](size_t bytes) -> void* {
    void* p = (void*)w;
    w += (bytes + 255) & ~(size_t)255;
    return p;
  };
  unsigned short* h1bf = (unsigned short*)alloc((size_t)NN*1024*2);  // conv1 out, bf16
  unsigned short* X2   = (unsigned short*)alloc((size_t)NN*512*2);   // [xl2 | xr2] bf16
  unsigned short* h2bf = (unsigned short*)alloc((size_t)NN*256*2);   // conv2 out, bf16
  float* X3   = (float*)alloc((size_t)NN*256*4);    // [xl3 | xr3] fp32
  float* h3   = (float*)alloc((size_t)NN*128*4);    // conv3 out (type0 rows only)
  unsigned short* W2lT = (unsigned short*)alloc((size_t)256*1024*2);
  unsigned short* W2rT = (unsigned short*)alloc((size_t)256*1024*2);
  unsigned short* W3lT = (unsigned short*)alloc((size_t)128*256*2);
  unsigned short* W3rT = (unsigned short*)alloc((size_t)128*256*2);
  float* Ul   = (float*)alloc(1024*4);
  float* CTl  = (float*)alloc(2048*4);
  float* Ur   = (float*)alloc(1024*4);
  float* CT2  = (float*)alloc(4096*4);
  float* scores = (float*)alloc((size_t)E2*8*4);
  const int zero_words = 3*NN;                       // deg, rowctr, loop_sum
  float* zbase = (float*)alloc((size_t)zero_words*4);
  int*   deg      = (int*)zbase;
  int*   rowctr   = (int*)(zbase + NN);
  float* loop_sum = zbase + 2*NN;
  float* loop_attr= (float*)alloc((size_t)NN*4);
  int*   rowptr   = (int*)alloc((size_t)(NN+1)*4);
  int*   srcs     = (int*)alloc((size_t)NE*4);
  int*   dsts     = (int*)alloc((size_t)NE*4);
  float* eav      = (float*)alloc((size_t)NE*4);

  // ---- pipeline (11 dispatches) ----
  prep_kernel<<<180, 256, 0, stream>>>(vp_w, vp_b, type_emb,
      c1_wl, c1_bl, c1_wr, c1_br, Ul, CTl, Ur, CT2,
      c2_wl, c2_wr, c3_wl, c3_wr, W2lT, W2rT, W3lT, W3rT,
      zbase, zero_words);
  count_kernel<<<(NE+255)/256, 256, 0, stream>>>(edst, eattr, deg, loop_sum);
  scan_kernel<<<1, 1024, 0, stream>>>(deg, loop_sum, rowptr, loop_attr);
  fill_kernel<<<(NE+255)/256, 256, 0, stream>>>(esrc, edst, eattr, rowptr, rowctr,
                                                srcs, dsts, eav);
  conv1_score<<<2048, 256, 0, stream>>>(srcs, dsts, eav, loop_attr, x, ntype,
      Ul, Ur, CT2, c1_we, c1_att, scores);
  conv1_agg<<<NN, 256, 0, stream>>>(rowptr, srcs, scores, x, ntype,
      Ul, CTl, c1_bias, h1bf);
  // c2: X2[10000,512] bf16, K=1024, NcH=256: cgrid=8, rgrid=79 -> 640 blocks
  gemm_dual_lds<true><<<640, 256, 0, stream>>>(
      (const short*)h1bf, (const short*)W2lT, (const short*)W2rT, c2_bl, c2_br,
      (void*)X2, NN, 1024, 256, 8, 79);
  conv_kernel<2,64,4,false,true,true><<<NN, 64, 0, stream>>>(rowptr, srcs, eav, loop_attr, ntype,
      (const void*)X2, 512, 256, c2_we, c2_att, c2_bias, h2bf);
  // c3: X3[10000,256] fp32, K=256, NcH=128: cgrid=4, rgrid=79 -> 320 blocks
  gemm_dual_lds<false><<<320, 256, 0, stream>>>(
      (const short*)h2bf, (const short*)W3lT, (const short*)W3rT, c3_bl, c3_br,
      (void*)X3, NN, 256, 128, 4, 79);
  conv_kernel<1,64,2,true,false,false><<<NN, 64, 0, stream>>>(rowptr, srcs, eav, loop_attr, ntype,
      (const void*)X3, 256, 128, c3_we, c3_att, c3_bias, h3);
  head_kernel<<<NBATCH, 128, 0, stream>>>(h3, ntype, batch, m1_w, m1_b, ln1_g, ln1_b,
                                          m2_w, m2_b, ln2_g, ln2_b, m3_w, m3_b, outp);
}